// Round 3
// baseline (1310.552 us; speedup 1.0000x reference)
//
#include <hip/hip_runtime.h>
#include <hip/hip_bf16.h>
#include <math.h>

#define N_NODES 50000
#define N_EDGES 150000
#define E2 (N_EDGES + N_NODES)
#define FDIM 325
#define HC 1300   // xlr row: [xl(650) | xr(650)], stored bf16

typedef unsigned short ushort_t;

__device__ __forceinline__ float bf2f(ushort_t u) {
  return __uint_as_float(((unsigned)u) << 16);
}
__device__ __forceinline__ ushort_t f2bf(float f) {
  __hip_bfloat16 h = __float2bfloat16(f);
  union { __hip_bfloat16 h; ushort_t u; } cv; cv.h = h;
  return cv.u;
}

__device__ __forceinline__ void atomicMaxF(float* addr, float v) {
  if (v >= 0.f) atomicMax((int*)addr, __float_as_int(v));
  else atomicMin((unsigned int*)addr, __float_as_uint(v));
}

// ---------------- init ----------------
__global__ void k_init(int* deg, int* cursor, float* mx, float* denom, float* acc, float* red) {
  int i = blockIdx.x * blockDim.x + threadIdx.x;
  if (i < N_NODES) { deg[i] = 0; cursor[i] = 0; }
  if (i < 2 * N_NODES) { mx[i] = -INFINITY; denom[i] = 0.f; }
  if (i < 5 * N_NODES) acc[i] = 0.f;
  if (i == 0) red[0] = 0.f;
}

// ---------------- degree count + edge-weight sum ----------------
__global__ void k_count(const int* __restrict__ dst, const float* __restrict__ ew,
                        int* deg, float* red) {
  int e = blockIdx.x * blockDim.x + threadIdx.x;
  float w = 0.f;
  if (e < N_EDGES) { atomicAdd(&deg[dst[e]], 1); w = ew[e]; }
  #pragma unroll
  for (int m = 32; m; m >>= 1) w += __shfl_xor(w, m);
  if ((threadIdx.x & 63) == 0) atomicAdd(red, w);
}

// ---------------- exclusive scan deg -> offs ----------------
__global__ void k_scan(const int* __restrict__ deg, int* offs) {
  __shared__ int carry;
  __shared__ int buf[1024];
  int tid = threadIdx.x;
  if (tid == 0) carry = 0;
  __syncthreads();
  for (int base = 0; base < N_NODES; base += 1024) {
    int i = base + tid;
    int v = (i < N_NODES) ? deg[i] : 0;
    buf[tid] = v;
    __syncthreads();
    for (int o = 1; o < 1024; o <<= 1) {
      int t = (tid >= o) ? buf[tid - o] : 0;
      __syncthreads();
      buf[tid] += t;
      __syncthreads();
    }
    int incl = buf[tid];
    int c = carry;
    __syncthreads();
    if (i < N_NODES) offs[i + 1] = c + incl;
    if (tid == 1023) carry = c + incl;
    __syncthreads();
  }
  if (tid == 0) offs[0] = 0;
}

// ---------------- scatter edges to CSR (by dst) ----------------
__global__ void k_scatter(const int* __restrict__ src, const int* __restrict__ dst,
                          const float* __restrict__ ew, const int* __restrict__ offs,
                          int* cursor, int* csr_src, float* csr_w) {
  int e = blockIdx.x * blockDim.x + threadIdx.x;
  if (e >= N_EDGES) return;
  int d = dst[e];
  int p = offs[d] + atomicAdd(&cursor[d], 1);
  csr_src[p] = src[e];
  csr_w[p] = ew[e];
}

// ---------------- fused 5x GCNConv aggregation -> x [N,325] bf16 ----------------
__global__ void __launch_bounds__(64) k_gcn(
    const float* __restrict__ h, const float* __restrict__ edge_num,
    const int* __restrict__ offs, const int* __restrict__ csr_src,
    const float* __restrict__ csr_w,
    const float* __restrict__ Wsum, const float* __restrict__ bsum,
    const float* __restrict__ Wmean, const float* __restrict__ bmean,
    const float* __restrict__ Wmax, const float* __restrict__ bmax,
    const float* __restrict__ Wne, const float* __restrict__ bne,
    const float* __restrict__ Wnem, const float* __restrict__ bnem,
    ushort_t* __restrict__ x) {
  int n = blockIdx.x;
  int t = threadIdx.x;
  float w0[5], w1[5], w2[5], w3[5], w4[5];
  #pragma unroll
  for (int k = 0; k < 5; ++k) {
    w0[k] = Wsum[k * 64 + t];
    w1[k] = Wmean[k * 64 + t];
    w2[k] = Wmax[k * 64 + t];
    w3[k] = Wne[k * 64 + t];
    w4[k] = Wnem[k * 64 + t];
  }
  float s_sum = 0.f, s_wmean = 0.f, s_max = -INFINITY, s_ne = 0.f, s_nem = -INFINITY;
  int beg = offs[n], end = offs[n + 1];
  for (int i = beg; i < end; ++i) {
    int s = csr_src[i];
    float w = csr_w[i];
    float hs[5];
    #pragma unroll
    for (int k = 0; k < 5; ++k) hs[k] = h[s * 5 + k];
    float v0 = 0, v1 = 0, v2 = 0, v3 = 0, v4 = 0;
    #pragma unroll
    for (int k = 0; k < 5; ++k) {
      v0 += hs[k] * w0[k]; v1 += hs[k] * w1[k]; v2 += hs[k] * w2[k];
      v3 += hs[k] * w3[k]; v4 += hs[k] * w4[k];
    }
    s_sum += w * v0;
    s_wmean += w * v1;
    s_max = fmaxf(s_max, w * v2);
    s_ne += v3;
    s_nem = fmaxf(s_nem, v4);
  }
  int dg = end - beg;
  float inv = 1.f / (float)(dg > 0 ? dg : 1);
  ushort_t* xr = x + (size_t)n * FDIM;
  xr[t]       = f2bf(s_sum + bsum[t]);
  xr[64 + t]  = f2bf(s_wmean * inv + bmean[t]);
  xr[128 + t] = f2bf((dg ? s_max : 0.f) + bmax[t]);
  xr[192 + t] = f2bf(s_ne + bne[t]);
  xr[256 + t] = f2bf((dg ? s_nem : 0.f) + bnem[t]);
  if (t < 5) xr[320 + t] = f2bf(edge_num[n * 5 + t]);
}

// ---------------- GEMM: xlr[N,1300] (bf16) = x[N,325] @ [Wl | Wr] ----------------
#define BM 128
#define BN 128
#define BK 16
__global__ void __launch_bounds__(256) k_gemm(
    const ushort_t* __restrict__ x, const float* __restrict__ Wl,
    const float* __restrict__ Wr, ushort_t* __restrict__ xlr) {
  __shared__ float As[BK][BM + 4];
  __shared__ float Bs[BK][BN + 4];
  int tid = threadIdx.x;
  int bm = blockIdx.x * BM;
  int bn = blockIdx.y * BN;
  int rowbase = (tid >> 4) << 3;
  int colbase = (tid & 15) << 3;
  float acc[8][8] = {};
  for (int k0 = 0; k0 < FDIM; k0 += BK) {
    {
      int k = tid & 15, m0 = tid >> 4;
      #pragma unroll
      for (int mm = m0; mm < BM; mm += 16) {
        int gm = bm + mm, gk = k0 + k;
        As[k][mm] = (gm < N_NODES && gk < FDIM) ? bf2f(x[(size_t)gm * FDIM + gk]) : 0.f;
      }
    }
    {
      int j = tid & 127, kk0 = tid >> 7;
      #pragma unroll
      for (int kk = kk0; kk < BK; kk += 2) {
        int gk = k0 + kk, gj = bn + j;
        float v = 0.f;
        if (gk < FDIM && gj < HC)
          v = (gj < 650) ? Wl[(size_t)gk * 650 + gj] : Wr[(size_t)gk * 650 + (gj - 650)];
        Bs[kk][j] = v;
      }
    }
    __syncthreads();
    #pragma unroll
    for (int kk = 0; kk < BK; ++kk) {
      float a[8], b[8];
      *(float4*)&a[0] = *(const float4*)&As[kk][rowbase];
      *(float4*)&a[4] = *(const float4*)&As[kk][rowbase + 4];
      *(float4*)&b[0] = *(const float4*)&Bs[kk][colbase];
      *(float4*)&b[4] = *(const float4*)&Bs[kk][colbase + 4];
      #pragma unroll
      for (int i = 0; i < 8; ++i)
        #pragma unroll
        for (int j = 0; j < 8; ++j) acc[i][j] += a[i] * b[j];
    }
    __syncthreads();
  }
  for (int i = 0; i < 8; ++i) {
    int gm = bm + rowbase + i;
    if (gm >= N_NODES) break;
    int gj = bn + colbase;
    if (gj + 7 < HC) {
      ushort4 u0, u1;
      u0.x = f2bf(acc[i][0]); u0.y = f2bf(acc[i][1]); u0.z = f2bf(acc[i][2]); u0.w = f2bf(acc[i][3]);
      u1.x = f2bf(acc[i][4]); u1.y = f2bf(acc[i][5]); u1.z = f2bf(acc[i][6]); u1.w = f2bf(acc[i][7]);
      *(ushort4*)&xlr[(size_t)gm * HC + gj]     = u0;
      *(ushort4*)&xlr[(size_t)gm * HC + gj + 4] = u1;
    } else {
      #pragma unroll
      for (int j = 0; j < 8; ++j)
        if (gj + j < HC) xlr[(size_t)gm * HC + gj + j] = f2bf(acc[i][j]);
    }
  }
}

// ---------------- Wlf[325,10] = per-head Wl @ Wfc fusion ----------------
__global__ void k_wlf(const float* __restrict__ Wl, const float* __restrict__ Wfc,
                      float* __restrict__ Wlf) {
  int t = blockIdx.x * blockDim.x + threadIdx.x;
  if (t >= FDIM * 10) return;
  int cp = t / 10, o = t % 10;
  int hh = o / 5, j = o % 5;
  float s = 0.f;
  for (int c = 0; c < 325; ++c) s += Wl[(size_t)cp * 650 + hh * 325 + c] * Wfc[c * 5 + j];
  Wlf[cp * 10 + o] = s;
}

// ---------------- yl[N,2,5] = x @ Wlf (f32 accumulate) ----------------
__global__ void k_yl(const ushort_t* __restrict__ x, const float* __restrict__ Wlf,
                     float* __restrict__ yl) {
  int wid = (blockIdx.x * blockDim.x + threadIdx.x) >> 6;
  int lane = threadIdx.x & 63;
  if (wid >= N_NODES) return;
  const ushort_t* row = x + (size_t)wid * FDIM;
  float p[10] = {};
  for (int c = lane; c < FDIM; c += 64) {
    float v = bf2f(row[c]);
    const float* wr = Wlf + c * 10;
    #pragma unroll
    for (int j = 0; j < 10; ++j) p[j] += v * wr[j];
  }
  #pragma unroll
  for (int j = 0; j < 10; ++j)
    #pragma unroll
    for (int m = 32; m; m >>= 1) p[j] += __shfl_xor(p[j], m);
  if (lane == 0) {
    #pragma unroll
    for (int j = 0; j < 10; ++j) yl[(size_t)wid * 10 + j] = p[j];
  }
}

// ---------------- cvec[j] = b_att @ W_fc1 + b_fc1 ; cvec[5] = mean(ew) ----------------
__global__ void k_cvec(const float* __restrict__ b_att, const float* __restrict__ Wfc,
                       const float* __restrict__ b_fc1, const float* __restrict__ red,
                       float* __restrict__ cvec) {
  int j = threadIdx.x;
  if (j == 5) cvec[5] = red[0] / (float)N_EDGES;
  if (j < 5) {
    float s = b_fc1[j];
    for (int c = 0; c < 325; ++c) s += b_att[c] * Wfc[c * 5 + j];
    cvec[j] = s;
  }
}

// ---------------- attention logits + segment max ----------------
__global__ void k_alpha(const int* __restrict__ src, const int* __restrict__ dst,
                        const float* __restrict__ ew, const ushort_t* __restrict__ xlr,
                        const float* __restrict__ We, const float* __restrict__ att,
                        const float* __restrict__ cvec, float* __restrict__ alphaE,
                        float* __restrict__ mx) {
  int w = (blockIdx.x * blockDim.x + threadIdx.x) >> 6;
  int lane = threadIdx.x & 63;
  if (w >= E2) return;
  int s, d; float ea;
  if (w < N_EDGES) { s = src[w]; d = dst[w]; ea = ew[w]; }
  else { s = d = w - N_EDGES; ea = cvec[5]; }
  const ushort_t* xs = xlr + (size_t)s * HC;        // xl: [2,325] flat 650
  const ushort_t* xd = xlr + (size_t)d * HC + 650;  // xr: [2,325] flat 650
  float p0 = 0.f, p1 = 0.f;
  for (int c = lane; c < 650; c += 64) {
    float v = bf2f(xs[c]) + bf2f(xd[c]) + ea * We[c];
    v = (v > 0.f) ? v : 0.2f * v;
    float t = v * att[c];
    if (c < 325) p0 += t; else p1 += t;
  }
  #pragma unroll
  for (int m = 32; m; m >>= 1) { p0 += __shfl_xor(p0, m); p1 += __shfl_xor(p1, m); }
  if (lane == 0) {
    alphaE[(size_t)w * 2]     = p0;
    alphaE[(size_t)w * 2 + 1] = p1;
    atomicMaxF(&mx[d * 2], p0);
    atomicMaxF(&mx[d * 2 + 1], p1);
  }
}

// ---------------- exp + segment sum ----------------
__global__ void k_expsum(const int* __restrict__ dst, float* __restrict__ alphaE,
                         const float* __restrict__ mx, float* __restrict__ denom) {
  int t = blockIdx.x * blockDim.x + threadIdx.x;
  if (t >= 2 * E2) return;
  int e = t >> 1, hh = t & 1;
  int d = (e < N_EDGES) ? dst[e] : e - N_EDGES;
  float a = __expf(alphaE[t] - mx[d * 2 + hh]);
  alphaE[t] = a;
  atomicAdd(&denom[d * 2 + hh], a);
}

// ---------------- normalized-weight accumulate of yl ----------------
__global__ void k_acc(const int* __restrict__ src, const int* __restrict__ dst,
                      const float* __restrict__ alphaE, const float* __restrict__ denom,
                      const float* __restrict__ yl, float* __restrict__ acc) {
  int e = blockIdx.x * blockDim.x + threadIdx.x;
  if (e >= E2) return;
  int s, d;
  if (e < N_EDGES) { s = src[e]; d = dst[e]; } else { s = d = e - N_EDGES; }
  float w0 = alphaE[(size_t)e * 2]     / denom[d * 2];
  float w1 = alphaE[(size_t)e * 2 + 1] / denom[d * 2 + 1];
  const float* y = yl + (size_t)s * 10;
  #pragma unroll
  for (int j = 0; j < 5; ++j)
    atomicAdd(&acc[(size_t)d * 5 + j], w0 * y[j] + w1 * y[5 + j]);
}

// ---------------- finalize ----------------
__global__ void k_final(const float* __restrict__ acc, const int* __restrict__ deg,
                        const float* __restrict__ cvec, float* __restrict__ out) {
  int t = blockIdx.x * blockDim.x + threadIdx.x;
  if (t >= 5 * N_NODES) return;
  int n = t / 5, j = t % 5;
  float inv = 1.f / (2.f * (float)(deg[n] + 1));
  out[t] = acc[t] * inv + cvec[j];
}

extern "C" void kernel_launch(void* const* d_in, const int* in_sizes, int n_in,
                              void* d_out, int out_size, void* d_ws, size_t ws_size,
                              hipStream_t stream) {
  (void)in_sizes; (void)n_in; (void)out_size; (void)ws_size;
  const float* h        = (const float*)d_in[0];
  const float* edge_num = (const float*)d_in[1];
  const int*   eidx     = (const int*)d_in[2];
  const float* ew       = (const float*)d_in[3];
  const float* Wsum  = (const float*)d_in[4];  const float* bsum  = (const float*)d_in[5];
  const float* Wmean = (const float*)d_in[6];  const float* bmean = (const float*)d_in[7];
  const float* Wmax  = (const float*)d_in[8];  const float* bmax  = (const float*)d_in[9];
  const float* Wne   = (const float*)d_in[10]; const float* bne   = (const float*)d_in[11];
  const float* Wnem  = (const float*)d_in[12]; const float* bnem  = (const float*)d_in[13];
  const float* Wl    = (const float*)d_in[14]; const float* Wr    = (const float*)d_in[15];
  const float* We    = (const float*)d_in[16]; const float* att   = (const float*)d_in[17];
  const float* b_att = (const float*)d_in[18];
  const float* Wfc   = (const float*)d_in[19]; const float* bfc   = (const float*)d_in[20];
  const int* src = eidx;
  const int* dst = eidx + N_EDGES;
  float* out = (float*)d_out;

  // workspace layout  (peak ~170 MB; round-0's 332 MB f32 layout likely overflowed d_ws)
  char* p = (char*)d_ws;
  size_t off = 0;
  auto alloc = [&](size_t bytes) { char* r = p + off; off = (off + bytes + 255) & ~(size_t)255; return r; };
  ushort_t* x      = (ushort_t*)alloc((size_t)N_NODES * FDIM * 2);   // 32.5 MB bf16
  ushort_t* xlr    = (ushort_t*)alloc((size_t)N_NODES * HC * 2);     // 130 MB bf16
  float* yl     = (float*)alloc((size_t)N_NODES * 10 * 4);
  float* alphaE = (float*)alloc((size_t)E2 * 2 * 4);
  int*   deg    = (int*)alloc((size_t)N_NODES * 4);
  int*   offs   = (int*)alloc((size_t)(N_NODES + 1) * 4);
  int*   cursor = (int*)alloc((size_t)N_NODES * 4);
  int*   csrs   = (int*)alloc((size_t)N_EDGES * 4);
  float* csrw   = (float*)alloc((size_t)N_EDGES * 4);
  float* mx     = (float*)alloc((size_t)2 * N_NODES * 4);
  float* denom  = (float*)alloc((size_t)2 * N_NODES * 4);
  float* acc    = (float*)alloc((size_t)5 * N_NODES * 4);
  float* Wlf    = (float*)alloc((size_t)FDIM * 10 * 4);
  float* red    = (float*)alloc(64);
  float* cvec   = (float*)alloc(64);

  k_init<<<(5 * N_NODES + 255) / 256, 256, 0, stream>>>(deg, cursor, mx, denom, acc, red);
  k_count<<<(N_EDGES + 255) / 256, 256, 0, stream>>>(dst, ew, deg, red);
  k_scan<<<1, 1024, 0, stream>>>(deg, offs);
  k_scatter<<<(N_EDGES + 255) / 256, 256, 0, stream>>>(src, dst, ew, offs, cursor, csrs, csrw);
  k_gcn<<<N_NODES, 64, 0, stream>>>(h, edge_num, offs, csrs, csrw,
                                    Wsum, bsum, Wmean, bmean, Wmax, bmax,
                                    Wne, bne, Wnem, bnem, x);
  dim3 gg((N_NODES + BM - 1) / BM, (HC + BN - 1) / BN);
  k_gemm<<<gg, 256, 0, stream>>>(x, Wl, Wr, xlr);
  k_wlf<<<(FDIM * 10 + 255) / 256, 256, 0, stream>>>(Wl, Wfc, Wlf);
  k_yl<<<(N_NODES * 64 + 255) / 256, 256, 0, stream>>>(x, Wlf, yl);
  k_cvec<<<1, 64, 0, stream>>>(b_att, Wfc, bfc, red, cvec);
  k_alpha<<<(E2 * 64 + 255) / 256, 256, 0, stream>>>(src, dst, ew, xlr, We, att, cvec, alphaE, mx);
  k_expsum<<<(2 * E2 + 255) / 256, 256, 0, stream>>>(dst, alphaE, mx, denom);
  k_acc<<<(E2 + 255) / 256, 256, 0, stream>>>(src, dst, alphaE, denom, yl, acc);
  k_final<<<(5 * N_NODES + 255) / 256, 256, 0, stream>>>(acc, deg, cvec, out);
}

// Round 5
// 661.545 us; speedup vs baseline: 1.9810x; 1.9810x over previous
//
#include <hip/hip_runtime.h>
#include <hip/hip_bf16.h>
#include <math.h>

#define N_NODES 50000
#define N_EDGES 150000
#define E2 (N_EDGES + N_NODES)
#define FDIM 325
#define KP 352      // K padded to multiple of 32 (and 16B alignment)
#define HC 1300     // xlr row: [xl(650) | xr(650)], stored bf16
#define LDA 40      // LDS tile row stride in ushorts (80B, 16B-aligned, bank-balanced)

typedef unsigned short ushort_t;
typedef __attribute__((ext_vector_type(8))) short short8v;
typedef __attribute__((ext_vector_type(4))) float f32x4;

__device__ __forceinline__ float bf2f(ushort_t u) {
  return __uint_as_float(((unsigned)u) << 16);
}
__device__ __forceinline__ ushort_t f2bf(float f) {
  __hip_bfloat16 h = __float2bfloat16(f);
  union { __hip_bfloat16 h; ushort_t u; } cv; cv.h = h;
  return cv.u;
}

__device__ __forceinline__ void atomicMaxF(float* addr, float v) {
  if (v >= 0.f) atomicMax((int*)addr, __float_as_int(v));
  else atomicMin((unsigned int*)addr, __float_as_uint(v));
}

// ---------------- init ----------------
__global__ void k_init(int* deg, int* cursor, float* mx, float* denom, float* acc, float* red) {
  int i = blockIdx.x * blockDim.x + threadIdx.x;
  if (i < N_NODES) { deg[i] = 0; cursor[i] = 0; }
  if (i < 2 * N_NODES) { mx[i] = -INFINITY; denom[i] = 0.f; }
  if (i < 5 * N_NODES) acc[i] = 0.f;
  if (i == 0) red[0] = 0.f;
}

// ---------------- degree count + edge-weight sum ----------------
__global__ void k_count(const int* __restrict__ dst, const float* __restrict__ ew,
                        int* deg, float* red) {
  int e = blockIdx.x * blockDim.x + threadIdx.x;
  float w = 0.f;
  if (e < N_EDGES) { atomicAdd(&deg[dst[e]], 1); w = ew[e]; }
  #pragma unroll
  for (int m = 32; m; m >>= 1) w += __shfl_xor(w, m);
  if ((threadIdx.x & 63) == 0) atomicAdd(red, w);
}

// ---------------- exclusive scan deg -> offs ----------------
__global__ void k_scan(const int* __restrict__ deg, int* offs) {
  __shared__ int carry;
  __shared__ int buf[1024];
  int tid = threadIdx.x;
  if (tid == 0) carry = 0;
  __syncthreads();
  for (int base = 0; base < N_NODES; base += 1024) {
    int i = base + tid;
    int v = (i < N_NODES) ? deg[i] : 0;
    buf[tid] = v;
    __syncthreads();
    for (int o = 1; o < 1024; o <<= 1) {
      int t = (tid >= o) ? buf[tid - o] : 0;
      __syncthreads();
      buf[tid] += t;
      __syncthreads();
    }
    int incl = buf[tid];
    int c = carry;
    __syncthreads();
    if (i < N_NODES) offs[i + 1] = c + incl;
    if (tid == 1023) carry = c + incl;
    __syncthreads();
  }
  if (tid == 0) offs[0] = 0;
}

// ---------------- scatter edges to CSR (by dst) ----------------
__global__ void k_scatter(const int* __restrict__ src, const int* __restrict__ dst,
                          const float* __restrict__ ew, const int* __restrict__ offs,
                          int* cursor, int* csr_src, float* csr_w) {
  int e = blockIdx.x * blockDim.x + threadIdx.x;
  if (e >= N_EDGES) return;
  int d = dst[e];
  int p = offs[d] + atomicAdd(&cursor[d], 1);
  csr_src[p] = src[e];
  csr_w[p] = ew[e];
}

// ---------------- fused 5x GCNConv aggregation -> x [N,KP] bf16 (K-padded) ----------------
__global__ void __launch_bounds__(64) k_gcn(
    const float* __restrict__ h, const float* __restrict__ edge_num,
    const int* __restrict__ offs, const int* __restrict__ csr_src,
    const float* __restrict__ csr_w,
    const float* __restrict__ Wsum, const float* __restrict__ bsum,
    const float* __restrict__ Wmean, const float* __restrict__ bmean,
    const float* __restrict__ Wmax, const float* __restrict__ bmax,
    const float* __restrict__ Wne, const float* __restrict__ bne,
    const float* __restrict__ Wnem, const float* __restrict__ bnem,
    ushort_t* __restrict__ x) {
  int n = blockIdx.x;
  int t = threadIdx.x;
  float w0[5], w1[5], w2[5], w3[5], w4[5];
  #pragma unroll
  for (int k = 0; k < 5; ++k) {
    w0[k] = Wsum[k * 64 + t];
    w1[k] = Wmean[k * 64 + t];
    w2[k] = Wmax[k * 64 + t];
    w3[k] = Wne[k * 64 + t];
    w4[k] = Wnem[k * 64 + t];
  }
  float s_sum = 0.f, s_wmean = 0.f, s_max = -INFINITY, s_ne = 0.f, s_nem = -INFINITY;
  int beg = offs[n], end = offs[n + 1];
  for (int i = beg; i < end; ++i) {
    int s = csr_src[i];
    float w = csr_w[i];
    float hs[5];
    #pragma unroll
    for (int k = 0; k < 5; ++k) hs[k] = h[s * 5 + k];
    float v0 = 0, v1 = 0, v2 = 0, v3 = 0, v4 = 0;
    #pragma unroll
    for (int k = 0; k < 5; ++k) {
      v0 += hs[k] * w0[k]; v1 += hs[k] * w1[k]; v2 += hs[k] * w2[k];
      v3 += hs[k] * w3[k]; v4 += hs[k] * w4[k];
    }
    s_sum += w * v0;
    s_wmean += w * v1;
    s_max = fmaxf(s_max, w * v2);
    s_ne += v3;
    s_nem = fmaxf(s_nem, v4);
  }
  int dg = end - beg;
  float inv = 1.f / (float)(dg > 0 ? dg : 1);
  ushort_t* xr = x + (size_t)n * KP;
  xr[t]       = f2bf(s_sum + bsum[t]);
  xr[64 + t]  = f2bf(s_wmean * inv + bmean[t]);
  xr[128 + t] = f2bf((dg ? s_max : 0.f) + bmax[t]);
  xr[192 + t] = f2bf(s_ne + bne[t]);
  xr[256 + t] = f2bf((dg ? s_nem : 0.f) + bnem[t]);
  if (t < 5) xr[320 + t] = f2bf(edge_num[n * 5 + t]);
  if (t < KP - FDIM) xr[FDIM + t] = 0;   // zero-pad K 325..351
}

// ---------------- Wt[1300][KP] bf16 = [Wl | Wr]^T, k-contiguous, zero-padded ----------------
__global__ void k_wt(const float* __restrict__ Wl, const float* __restrict__ Wr,
                     ushort_t* __restrict__ Wt) {
  int t = blockIdx.x * blockDim.x + threadIdx.x;
  if (t >= HC * KP) return;
  int n = t / KP, k = t % KP;
  float v = 0.f;
  if (k < FDIM) v = (n < 650) ? Wl[(size_t)k * 650 + n] : Wr[(size_t)k * 650 + (n - 650)];
  Wt[t] = f2bf(v);
}

// ---------------- MFMA GEMM: xlr[N,1300] (bf16) = x[N,325] @ [Wl|Wr] ----------------
__global__ void __launch_bounds__(256) k_gemm_mfma(
    const ushort_t* __restrict__ x, const ushort_t* __restrict__ Wt,
    ushort_t* __restrict__ xlr) {
  __shared__ ushort_t As[128 * LDA];
  __shared__ ushort_t Bs[128 * LDA];
  int tid = threadIdx.x;
  int lane = tid & 63, wave = tid >> 6;
  int wr = wave >> 1, wc = wave & 1;         // 2x2 waves, each owns 64x64 of C
  int bm = blockIdx.x * 128, bn = blockIdx.y * 128;
  f32x4 acc[4][4] = {};
  for (int k0 = 0; k0 < KP; k0 += 32) {
    #pragma unroll
    for (int it = 0; it < 2; ++it) {
      int idx = tid + it * 256;              // 0..511
      int row = idx >> 2, kc = (idx & 3) << 3;
      int gm = bm + row;
      float4 av = make_float4(0.f, 0.f, 0.f, 0.f);
      if (gm < N_NODES) av = *(const float4*)&x[(size_t)gm * KP + k0 + kc];
      *(float4*)&As[row * LDA + kc] = av;
      int gn = bn + row;
      float4 bv = make_float4(0.f, 0.f, 0.f, 0.f);
      if (gn < HC) bv = *(const float4*)&Wt[(size_t)gn * KP + k0 + kc];
      *(float4*)&Bs[row * LDA + kc] = bv;
    }
    __syncthreads();
    int koff = (lane >> 4) << 3;             // 0,8,16,24
    int ar = (wr << 6) + (lane & 15);
    int br = (wc << 6) + (lane & 15);
    short8v a[4], b[4];
    #pragma unroll
    for (int i = 0; i < 4; ++i) a[i] = *(const short8v*)&As[(ar + i * 16) * LDA + koff];
    #pragma unroll
    for (int j = 0; j < 4; ++j) b[j] = *(const short8v*)&Bs[(br + j * 16) * LDA + koff];
    #pragma unroll
    for (int i = 0; i < 4; ++i)
      #pragma unroll
      for (int j = 0; j < 4; ++j)
        acc[i][j] = __builtin_amdgcn_mfma_f32_16x16x32_bf16(a[i], b[j], acc[i][j], 0, 0, 0);
    __syncthreads();
  }
  // C/D layout: col = lane&15, row = (lane>>4)*4 + reg
  int rbase = bm + (wr << 6) + ((lane >> 4) << 2);
  int cbase = bn + (wc << 6) + (lane & 15);
  #pragma unroll
  for (int i = 0; i < 4; ++i) {
    #pragma unroll
    for (int j = 0; j < 4; ++j) {
      int col = cbase + j * 16;
      if (col >= HC) continue;
      #pragma unroll
      for (int r = 0; r < 4; ++r) {
        int row = rbase + i * 16 + r;
        if (row < N_NODES) xlr[(size_t)row * HC + col] = f2bf(acc[i][j][r]);
      }
    }
  }
}

// ---------------- Wlf[325,10] = per-head Wl @ Wfc fusion ----------------
__global__ void k_wlf(const float* __restrict__ Wl, const float* __restrict__ Wfc,
                      float* __restrict__ Wlf) {
  int t = blockIdx.x * blockDim.x + threadIdx.x;
  if (t >= FDIM * 10) return;
  int cp = t / 10, o = t % 10;
  int hh = o / 5, j = o % 5;
  float s = 0.f;
  for (int c = 0; c < 325; ++c) s += Wl[(size_t)cp * 650 + hh * 325 + c] * Wfc[c * 5 + j];
  Wlf[cp * 10 + o] = s;
}

// ---------------- yl[N,2,5] = x @ Wlf (f32 accumulate) ----------------
__global__ void k_yl(const ushort_t* __restrict__ x, const float* __restrict__ Wlf,
                     float* __restrict__ yl) {
  int wid = (blockIdx.x * blockDim.x + threadIdx.x) >> 6;
  int lane = threadIdx.x & 63;
  if (wid >= N_NODES) return;
  const ushort_t* row = x + (size_t)wid * KP;
  float p[10] = {};
  for (int c = lane; c < FDIM; c += 64) {
    float v = bf2f(row[c]);
    const float* wr = Wlf + c * 10;
    #pragma unroll
    for (int j = 0; j < 10; ++j) p[j] += v * wr[j];
  }
  #pragma unroll
  for (int j = 0; j < 10; ++j)
    #pragma unroll
    for (int m = 32; m; m >>= 1) p[j] += __shfl_xor(p[j], m);
  if (lane == 0) {
    #pragma unroll
    for (int j = 0; j < 10; ++j) yl[(size_t)wid * 10 + j] = p[j];
  }
}

// ---------------- cvec[j] = b_att @ W_fc1 + b_fc1 ; cvec[5] = mean(ew) ----------------
__global__ void k_cvec(const float* __restrict__ b_att, const float* __restrict__ Wfc,
                       const float* __restrict__ b_fc1, const float* __restrict__ red,
                       float* __restrict__ cvec) {
  int j = threadIdx.x;
  if (j == 5) cvec[5] = red[0] / (float)N_EDGES;
  if (j < 5) {
    float s = b_fc1[j];
    for (int c = 0; c < 325; ++c) s += b_att[c] * Wfc[c * 5 + j];
    cvec[j] = s;
  }
}

// ---------------- attention logits + segment max ----------------
__global__ void k_alpha(const int* __restrict__ src, const int* __restrict__ dst,
                        const float* __restrict__ ew, const ushort_t* __restrict__ xlr,
                        const float* __restrict__ We, const float* __restrict__ att,
                        const float* __restrict__ cvec, float* __restrict__ alphaE,
                        float* __restrict__ mx) {
  int w = (blockIdx.x * blockDim.x + threadIdx.x) >> 6;
  int lane = threadIdx.x & 63;
  if (w >= E2) return;
  int s, d; float ea;
  if (w < N_EDGES) { s = src[w]; d = dst[w]; ea = ew[w]; }
  else { s = d = w - N_EDGES; ea = cvec[5]; }
  const ushort_t* xs = xlr + (size_t)s * HC;        // xl: [2,325] flat 650
  const ushort_t* xd = xlr + (size_t)d * HC + 650;  // xr: [2,325] flat 650
  float p0 = 0.f, p1 = 0.f;
  for (int c = lane; c < 650; c += 64) {
    float v = bf2f(xs[c]) + bf2f(xd[c]) + ea * We[c];
    v = (v > 0.f) ? v : 0.2f * v;
    float t = v * att[c];
    if (c < 325) p0 += t; else p1 += t;
  }
  #pragma unroll
  for (int m = 32; m; m >>= 1) { p0 += __shfl_xor(p0, m); p1 += __shfl_xor(p1, m); }
  if (lane == 0) {
    alphaE[(size_t)w * 2]     = p0;
    alphaE[(size_t)w * 2 + 1] = p1;
    atomicMaxF(&mx[d * 2], p0);
    atomicMaxF(&mx[d * 2 + 1], p1);
  }
}

// ---------------- exp + segment sum ----------------
__global__ void k_expsum(const int* __restrict__ dst, float* __restrict__ alphaE,
                         const float* __restrict__ mx, float* __restrict__ denom) {
  int t = blockIdx.x * blockDim.x + threadIdx.x;
  if (t >= 2 * E2) return;
  int e = t >> 1, hh = t & 1;
  int d = (e < N_EDGES) ? dst[e] : e - N_EDGES;
  float a = __expf(alphaE[t] - mx[d * 2 + hh]);
  alphaE[t] = a;
  atomicAdd(&denom[d * 2 + hh], a);
}

// ---------------- normalized-weight accumulate of yl ----------------
__global__ void k_acc(const int* __restrict__ src, const int* __restrict__ dst,
                      const float* __restrict__ alphaE, const float* __restrict__ denom,
                      const float* __restrict__ yl, float* __restrict__ acc) {
  int e = blockIdx.x * blockDim.x + threadIdx.x;
  if (e >= E2) return;
  int s, d;
  if (e < N_EDGES) { s = src[e]; d = dst[e]; } else { s = d = e - N_EDGES; }
  float w0 = alphaE[(size_t)e * 2]     / denom[d * 2];
  float w1 = alphaE[(size_t)e * 2 + 1] / denom[d * 2 + 1];
  const float* y = yl + (size_t)s * 10;
  #pragma unroll
  for (int j = 0; j < 5; ++j)
    atomicAdd(&acc[(size_t)d * 5 + j], w0 * y[j] + w1 * y[5 + j]);
}

// ---------------- finalize ----------------
__global__ void k_final(const float* __restrict__ acc, const int* __restrict__ deg,
                        const float* __restrict__ cvec, float* __restrict__ out) {
  int t = blockIdx.x * blockDim.x + threadIdx.x;
  if (t >= 5 * N_NODES) return;
  int n = t / 5, j = t % 5;
  float inv = 1.f / (2.f * (float)(deg[n] + 1));
  out[t] = acc[t] * inv + cvec[j];
}

extern "C" void kernel_launch(void* const* d_in, const int* in_sizes, int n_in,
                              void* d_out, int out_size, void* d_ws, size_t ws_size,
                              hipStream_t stream) {
  (void)in_sizes; (void)n_in; (void)out_size; (void)ws_size;
  const float* h        = (const float*)d_in[0];
  const float* edge_num = (const float*)d_in[1];
  const int*   eidx     = (const int*)d_in[2];
  const float* ew       = (const float*)d_in[3];
  const float* Wsum  = (const float*)d_in[4];  const float* bsum  = (const float*)d_in[5];
  const float* Wmean = (const float*)d_in[6];  const float* bmean = (const float*)d_in[7];
  const float* Wmax  = (const float*)d_in[8];  const float* bmax  = (const float*)d_in[9];
  const float* Wne   = (const float*)d_in[10]; const float* bne   = (const float*)d_in[11];
  const float* Wnem  = (const float*)d_in[12]; const float* bnem  = (const float*)d_in[13];
  const float* Wl    = (const float*)d_in[14]; const float* Wr    = (const float*)d_in[15];
  const float* We    = (const float*)d_in[16]; const float* att   = (const float*)d_in[17];
  const float* b_att = (const float*)d_in[18];
  const float* Wfc   = (const float*)d_in[19]; const float* bfc   = (const float*)d_in[20];
  const int* src = eidx;
  const int* dst = eidx + N_EDGES;
  float* out = (float*)d_out;

  // workspace layout (~175 MB peak)
  char* p = (char*)d_ws;
  size_t off = 0;
  auto alloc = [&](size_t bytes) { char* r = p + off; off = (off + bytes + 255) & ~(size_t)255; return r; };
  ushort_t* x   = (ushort_t*)alloc((size_t)N_NODES * KP * 2);   // 35.2 MB bf16 (K-padded)
  ushort_t* xlr = (ushort_t*)alloc((size_t)N_NODES * HC * 2);   // 130 MB bf16
  ushort_t* Wt  = (ushort_t*)alloc((size_t)HC * KP * 2);        // 0.9 MB bf16
  float* yl     = (float*)alloc((size_t)N_NODES * 10 * 4);
  float* alphaE = (float*)alloc((size_t)E2 * 2 * 4);
  int*   deg    = (int*)alloc((size_t)N_NODES * 4);
  int*   offs   = (int*)alloc((size_t)(N_NODES + 1) * 4);
  int*   cursor = (int*)alloc((size_t)N_NODES * 4);
  int*   csrs   = (int*)alloc((size_t)N_EDGES * 4);
  float* csrw   = (float*)alloc((size_t)N_EDGES * 4);
  float* mx     = (float*)alloc((size_t)2 * N_NODES * 4);
  float* denom  = (float*)alloc((size_t)2 * N_NODES * 4);
  float* acc    = (float*)alloc((size_t)5 * N_NODES * 4);
  float* Wlf    = (float*)alloc((size_t)FDIM * 10 * 4);
  float* red    = (float*)alloc(64);
  float* cvec   = (float*)alloc(64);

  k_init<<<(5 * N_NODES + 255) / 256, 256, 0, stream>>>(deg, cursor, mx, denom, acc, red);
  k_count<<<(N_EDGES + 255) / 256, 256, 0, stream>>>(dst, ew, deg, red);
  k_scan<<<1, 1024, 0, stream>>>(deg, offs);
  k_scatter<<<(N_EDGES + 255) / 256, 256, 0, stream>>>(src, dst, ew, offs, cursor, csrs, csrw);
  k_gcn<<<N_NODES, 64, 0, stream>>>(h, edge_num, offs, csrs, csrw,
                                    Wsum, bsum, Wmean, bmean, Wmax, bmax,
                                    Wne, bne, Wnem, bnem, x);
  k_wt<<<(HC * KP + 255) / 256, 256, 0, stream>>>(Wl, Wr, Wt);
  dim3 gg((N_NODES + 127) / 128, (HC + 127) / 128);
  k_gemm_mfma<<<gg, 256, 0, stream>>>(x, Wt, xlr);
  k_wlf<<<(FDIM * 10 + 255) / 256, 256, 0, stream>>>(Wl, Wfc, Wlf);
  k_yl<<<(N_NODES * 64 + 255) / 256, 256, 0, stream>>>(x, Wlf, yl);
  k_cvec<<<1, 64, 0, stream>>>(b_att, Wfc, bfc, red, cvec);
  k_alpha<<<(E2 * 64 + 255) / 256, 256, 0, stream>>>(src, dst, ew, xlr, We, att, cvec, alphaE, mx);
  k_expsum<<<(2 * E2 + 255) / 256, 256, 0, stream>>>(dst, alphaE, mx, denom);
  k_acc<<<(E2 + 255) / 256, 256, 0, stream>>>(src, dst, alphaE, denom, yl, acc);
  k_final<<<(5 * N_NODES + 255) / 256, 256, 0, stream>>>(acc, deg, cvec, out);
}

// Round 9
// 546.435 us; speedup vs baseline: 2.3984x; 1.2107x over previous
//
#include <hip/hip_runtime.h>
#include <hip/hip_bf16.h>
#include <math.h>

#define N_NODES 50000
#define N_EDGES 150000
#define E2 (N_EDGES + N_NODES)
#define FDIM 325
#define KP 352      // K padded to multiple of 32 (and 16B alignment)
#define HC 1300     // xlr row: [xl(650) | xr(650)], stored bf16
#define LDA 40      // LDS tile row stride in ushorts (80B, 16B-aligned, bank-balanced)

typedef unsigned short ushort_t;
typedef __attribute__((ext_vector_type(8))) short short8v;
typedef __attribute__((ext_vector_type(4))) float f32x4;

__device__ __forceinline__ float bf2f(ushort_t u) {
  return __uint_as_float(((unsigned)u) << 16);
}
__device__ __forceinline__ ushort_t f2bf(float f) {
  __hip_bfloat16 h = __float2bfloat16(f);
  union { __hip_bfloat16 h; ushort_t u; } cv; cv.h = h;
  return cv.u;
}

// ---------------- init ----------------
__global__ void k_init(int* deg, int* cursor, float* red) {
  int i = blockIdx.x * blockDim.x + threadIdx.x;
  if (i < N_NODES) { deg[i] = 0; cursor[i] = 0; }
  if (i == 0) red[0] = 0.f;
}

// ---------------- degree count + edge-weight sum ----------------
__global__ void k_count(const int* __restrict__ dst, const float* __restrict__ ew,
                        int* deg, float* red) {
  int e = blockIdx.x * blockDim.x + threadIdx.x;
  float w = 0.f;
  if (e < N_EDGES) { atomicAdd(&deg[dst[e]], 1); w = ew[e]; }
  #pragma unroll
  for (int m = 32; m; m >>= 1) w += __shfl_xor(w, m);
  if ((threadIdx.x & 63) == 0) atomicAdd(red, w);
}

// ---------------- exclusive scan deg -> offs ----------------
__global__ void k_scan(const int* __restrict__ deg, int* offs) {
  __shared__ int carry;
  __shared__ int buf[1024];
  int tid = threadIdx.x;
  if (tid == 0) carry = 0;
  __syncthreads();
  for (int base = 0; base < N_NODES; base += 1024) {
    int i = base + tid;
    int v = (i < N_NODES) ? deg[i] : 0;
    buf[tid] = v;
    __syncthreads();
    for (int o = 1; o < 1024; o <<= 1) {
      int t = (tid >= o) ? buf[tid - o] : 0;
      __syncthreads();
      buf[tid] += t;
      __syncthreads();
    }
    int incl = buf[tid];
    int c = carry;
    __syncthreads();
    if (i < N_NODES) offs[i + 1] = c + incl;
    if (tid == 1023) carry = c + incl;
    __syncthreads();
  }
  if (tid == 0) offs[0] = 0;
}

// ---------------- scatter edges to CSR (by dst) ----------------
__global__ void k_scatter(const int* __restrict__ src, const int* __restrict__ dst,
                          const float* __restrict__ ew, const int* __restrict__ offs,
                          int* cursor, int* csr_src, float* csr_w) {
  int e = blockIdx.x * blockDim.x + threadIdx.x;
  if (e >= N_EDGES) return;
  int d = dst[e];
  int p = offs[d] + atomicAdd(&cursor[d], 1);
  csr_src[p] = src[e];
  csr_w[p] = ew[e];
}

// ---------------- fused 5x GCNConv aggregation -> x [N,KP] bf16 (K-padded) ----------------
__global__ void __launch_bounds__(64) k_gcn(
    const float* __restrict__ h, const float* __restrict__ edge_num,
    const int* __restrict__ offs, const int* __restrict__ csr_src,
    const float* __restrict__ csr_w,
    const float* __restrict__ Wsum, const float* __restrict__ bsum,
    const float* __restrict__ Wmean, const float* __restrict__ bmean,
    const float* __restrict__ Wmax, const float* __restrict__ bmax,
    const float* __restrict__ Wne, const float* __restrict__ bne,
    const float* __restrict__ Wnem, const float* __restrict__ bnem,
    ushort_t* __restrict__ x) {
  int n = blockIdx.x;
  int t = threadIdx.x;
  float w0[5], w1[5], w2[5], w3[5], w4[5];
  #pragma unroll
  for (int k = 0; k < 5; ++k) {
    w0[k] = Wsum[k * 64 + t];
    w1[k] = Wmean[k * 64 + t];
    w2[k] = Wmax[k * 64 + t];
    w3[k] = Wne[k * 64 + t];
    w4[k] = Wnem[k * 64 + t];
  }
  float s_sum = 0.f, s_wmean = 0.f, s_max = -INFINITY, s_ne = 0.f, s_nem = -INFINITY;
  int beg = offs[n], end = offs[n + 1];
  for (int i = beg; i < end; ++i) {
    int s = csr_src[i];
    float w = csr_w[i];
    float hs[5];
    #pragma unroll
    for (int k = 0; k < 5; ++k) hs[k] = h[s * 5 + k];
    float v0 = 0, v1 = 0, v2 = 0, v3 = 0, v4 = 0;
    #pragma unroll
    for (int k = 0; k < 5; ++k) {
      v0 += hs[k] * w0[k]; v1 += hs[k] * w1[k]; v2 += hs[k] * w2[k];
      v3 += hs[k] * w3[k]; v4 += hs[k] * w4[k];
    }
    s_sum += w * v0;
    s_wmean += w * v1;
    s_max = fmaxf(s_max, w * v2);
    s_ne += v3;
    s_nem = fmaxf(s_nem, v4);
  }
  int dg = end - beg;
  float inv = 1.f / (float)(dg > 0 ? dg : 1);
  ushort_t* xr = x + (size_t)n * KP;
  xr[t]       = f2bf(s_sum + bsum[t]);
  xr[64 + t]  = f2bf(s_wmean * inv + bmean[t]);
  xr[128 + t] = f2bf((dg ? s_max : 0.f) + bmax[t]);
  xr[192 + t] = f2bf(s_ne + bne[t]);
  xr[256 + t] = f2bf((dg ? s_nem : 0.f) + bnem[t]);
  if (t < 5) xr[320 + t] = f2bf(edge_num[n * 5 + t]);
  if (t < KP - FDIM) xr[FDIM + t] = 0;   // zero-pad K 325..351
}

// ---------------- Wt[1300][KP] bf16 = [Wl | Wr]^T, k-contiguous, zero-padded ----------------
__global__ void k_wt(const float* __restrict__ Wl, const float* __restrict__ Wr,
                     ushort_t* __restrict__ Wt) {
  int t = blockIdx.x * blockDim.x + threadIdx.x;
  if (t >= HC * KP) return;
  int n = t / KP, k = t % KP;
  float v = 0.f;
  if (k < FDIM) v = (n < 650) ? Wl[(size_t)k * 650 + n] : Wr[(size_t)k * 650 + (n - 650)];
  Wt[t] = f2bf(v);
}

// ---------------- MFMA GEMM: xlr[N,1300] (bf16) = x[N,325] @ [Wl|Wr] ----------------
// grid = (N-blocks of bn, M-blocks of bm): bn fastest so the 11 blocks sharing
// one A-panel dispatch consecutively -> A read once via L2/L3 (was 2.2x over-fetch)
__global__ void __launch_bounds__(256) k_gemm_mfma(
    const ushort_t* __restrict__ x, const ushort_t* __restrict__ Wt,
    ushort_t* __restrict__ xlr) {
  __shared__ ushort_t As[128 * LDA];
  __shared__ ushort_t Bs[128 * LDA];
  int tid = threadIdx.x;
  int lane = tid & 63, wave = tid >> 6;
  int wr = wave >> 1, wc = wave & 1;         // 2x2 waves, each owns 64x64 of C
  int bm = blockIdx.y * 128, bn = blockIdx.x * 128;
  f32x4 acc[4][4] = {};
  for (int k0 = 0; k0 < KP; k0 += 32) {
    #pragma unroll
    for (int it = 0; it < 2; ++it) {
      int idx = tid + it * 256;              // 0..511
      int row = idx >> 2, kc = (idx & 3) << 3;
      int gm = bm + row;
      float4 av = make_float4(0.f, 0.f, 0.f, 0.f);
      if (gm < N_NODES) av = *(const float4*)&x[(size_t)gm * KP + k0 + kc];
      *(float4*)&As[row * LDA + kc] = av;
      int gn = bn + row;
      float4 bv = make_float4(0.f, 0.f, 0.f, 0.f);
      if (gn < HC) bv = *(const float4*)&Wt[(size_t)gn * KP + k0 + kc];
      *(float4*)&Bs[row * LDA + kc] = bv;
    }
    __syncthreads();
    int koff = (lane >> 4) << 3;             // 0,8,16,24
    int ar = (wr << 6) + (lane & 15);
    int br = (wc << 6) + (lane & 15);
    short8v a[4], b[4];
    #pragma unroll
    for (int i = 0; i < 4; ++i) a[i] = *(const short8v*)&As[(ar + i * 16) * LDA + koff];
    #pragma unroll
    for (int j = 0; j < 4; ++j) b[j] = *(const short8v*)&Bs[(br + j * 16) * LDA + koff];
    #pragma unroll
    for (int i = 0; i < 4; ++i)
      #pragma unroll
      for (int j = 0; j < 4; ++j)
        acc[i][j] = __builtin_amdgcn_mfma_f32_16x16x32_bf16(a[i], b[j], acc[i][j], 0, 0, 0);
    __syncthreads();
  }
  // C/D layout: col = lane&15, row = (lane>>4)*4 + reg
  int rbase = bm + (wr << 6) + ((lane >> 4) << 2);
  int cbase = bn + (wc << 6) + (lane & 15);
  #pragma unroll
  for (int i = 0; i < 4; ++i) {
    #pragma unroll
    for (int j = 0; j < 4; ++j) {
      int col = cbase + j * 16;
      if (col >= HC) continue;
      #pragma unroll
      for (int r = 0; r < 4; ++r) {
        int row = rbase + i * 16 + r;
        if (row < N_NODES) xlr[(size_t)row * HC + col] = f2bf(acc[i][j][r]);
      }
    }
  }
}

// ---------------- Wlf[325,10] = per-head Wl @ Wfc fusion ----------------
__global__ void k_wlf(const float* __restrict__ Wl, const float* __restrict__ Wfc,
                      float* __restrict__ Wlf) {
  int t = blockIdx.x * blockDim.x + threadIdx.x;
  if (t >= FDIM * 10) return;
  int cp = t / 10, o = t % 10;
  int hh = o / 5, j = o % 5;
  float s = 0.f;
  for (int c = 0; c < 325; ++c) s += Wl[(size_t)cp * 650 + hh * 325 + c] * Wfc[c * 5 + j];
  Wlf[cp * 10 + o] = s;
}

// ---------------- yl[N,2,5] = x @ Wlf (f32 accumulate) ----------------
__global__ void k_yl(const ushort_t* __restrict__ x, const float* __restrict__ Wlf,
                     float* __restrict__ yl) {
  int wid = (blockIdx.x * blockDim.x + threadIdx.x) >> 6;
  int lane = threadIdx.x & 63;
  if (wid >= N_NODES) return;
  const ushort_t* row = x + (size_t)wid * KP;
  float p[10] = {};
  for (int c = lane; c < FDIM; c += 64) {
    float v = bf2f(row[c]);
    const float* wr = Wlf + c * 10;
    #pragma unroll
    for (int j = 0; j < 10; ++j) p[j] += v * wr[j];
  }
  #pragma unroll
  for (int j = 0; j < 10; ++j)
    #pragma unroll
    for (int m = 32; m; m >>= 1) p[j] += __shfl_xor(p[j], m);
  if (lane == 0) {
    #pragma unroll
    for (int j = 0; j < 10; ++j) yl[(size_t)wid * 10 + j] = p[j];
  }
}

// ---------------- cvec[j] = b_att @ W_fc1 + b_fc1 ; cvec[5] = mean(ew) ----------------
__global__ void k_cvec(const float* __restrict__ b_att, const float* __restrict__ Wfc,
                       const float* __restrict__ b_fc1, const float* __restrict__ red,
                       float* __restrict__ cvec) {
  int j = threadIdx.x;
  if (j == 5) cvec[5] = red[0] / (float)N_EDGES;
  if (j < 5) {
    float s = b_fc1[j];
    for (int c = 0; c < 325; ++c) s += b_att[c] * Wfc[c * 5 + j];
    cvec[j] = s;
  }
}

// ---------------- fused GATv2 attention: per-dst online softmax + aggregate ----------------
// one wave per dst node d: xr[d], We, att in registers (11 slots/lane);
// stream xl[src] per incoming edge + self-loop; flash-style running (m,s,o).
__global__ void __launch_bounds__(256) k_att(
    const int* __restrict__ offs, const int* __restrict__ csrs,
    const float* __restrict__ csrw, const ushort_t* __restrict__ xlr,
    const float* __restrict__ We, const float* __restrict__ att,
    const float* __restrict__ cvec, const float* __restrict__ yl,
    float* __restrict__ out) {
  int d = (blockIdx.x * blockDim.x + threadIdx.x) >> 6;
  int lane = threadIdx.x & 63;
  if (d >= N_NODES) return;
  // per-lane c-slots: c = j*64 + lane (j=0..10; j=10 valid only for lane<10)
  float xdv[11], Wev[11], attv[11];
  const ushort_t* xd = xlr + (size_t)d * HC + 650;
  #pragma unroll
  for (int j = 0; j < 11; ++j) {
    int c = j * 64 + lane;
    bool ok = c < 650;
    xdv[j]  = ok ? bf2f(xd[c]) : 0.f;
    Wev[j]  = ok ? We[c] : 0.f;
    attv[j] = ok ? att[c] : 0.f;
  }
  float meanw = cvec[5];
  int beg = offs[d], end = offs[d + 1];
  float m0 = -INFINITY, m1 = -INFINITY, s0 = 0.f, s1 = 0.f;
  float oj = 0.f;   // lanes 0..9 hold o_j (j<5: head0 dims, j>=5: head1 dims)
  for (int i = beg; i <= end; ++i) {   // i == end -> self-loop
    int s; float ea;
    if (i < end) { s = csrs[i]; ea = csrw[i]; }
    else { s = d; ea = meanw; }
    const ushort_t* xs = xlr + (size_t)s * HC;
    float p0 = 0.f, p1 = 0.f;
    #pragma unroll
    for (int j = 0; j < 11; ++j) {
      int c = j * 64 + lane;
      if (c < 650) {
        float v = bf2f(xs[c]) + xdv[j] + ea * Wev[j];
        v = (v > 0.f) ? v : 0.2f * v;
        float t = v * attv[j];
        if (c < 325) p0 += t; else p1 += t;
      }
    }
    #pragma unroll
    for (int m = 32; m; m >>= 1) { p0 += __shfl_xor(p0, m); p1 += __shfl_xor(p1, m); }
    float nm0 = fmaxf(m0, p0), nm1 = fmaxf(m1, p1);
    float r0 = __expf(m0 - nm0), r1 = __expf(m1 - nm1);  // first iter: exp(-inf)=0
    float e0 = __expf(p0 - nm0), e1 = __expf(p1 - nm1);
    s0 = s0 * r0 + e0; s1 = s1 * r1 + e1;
    m0 = nm0; m1 = nm1;
    if (lane < 10) {
      float yv = yl[(size_t)s * 10 + lane];
      float r = (lane < 5) ? r0 : r1;
      float e = (lane < 5) ? e0 : e1;
      oj = oj * r + e * yv;
    }
  }
  float on = oj / ((lane < 5) ? s0 : s1);
  float other = __shfl(on, lane + 5);
  if (lane < 5) {
    int dg = end - beg;
    out[(size_t)d * 5 + lane] = (on + other) / (2.f * (float)(dg + 1)) + cvec[lane];
  }
}

extern "C" void kernel_launch(void* const* d_in, const int* in_sizes, int n_in,
                              void* d_out, int out_size, void* d_ws, size_t ws_size,
                              hipStream_t stream) {
  (void)in_sizes; (void)n_in; (void)out_size; (void)ws_size;
  const float* h        = (const float*)d_in[0];
  const float* edge_num = (const float*)d_in[1];
  const int*   eidx     = (const int*)d_in[2];
  const float* ew       = (const float*)d_in[3];
  const float* Wsum  = (const float*)d_in[4];  const float* bsum  = (const float*)d_in[5];
  const float* Wmean = (const float*)d_in[6];  const float* bmean = (const float*)d_in[7];
  const float* Wmax  = (const float*)d_in[8];  const float* bmax  = (const float*)d_in[9];
  const float* Wne   = (const float*)d_in[10]; const float* bne   = (const float*)d_in[11];
  const float* Wnem  = (const float*)d_in[12]; const float* bnem  = (const float*)d_in[13];
  const float* Wl    = (const float*)d_in[14]; const float* Wr    = (const float*)d_in[15];
  const float* We    = (const float*)d_in[16]; const float* att   = (const float*)d_in[17];
  const float* b_att = (const float*)d_in[18];
  const float* Wfc   = (const float*)d_in[19]; const float* bfc   = (const float*)d_in[20];
  const int* src = eidx;
  const int* dst = eidx + N_EDGES;
  float* out = (float*)d_out;

  // workspace layout (~170 MB peak)
  char* p = (char*)d_ws;
  size_t off = 0;
  auto alloc = [&](size_t bytes) { char* r = p + off; off = (off + bytes + 255) & ~(size_t)255; return r; };
  ushort_t* x   = (ushort_t*)alloc((size_t)N_NODES * KP * 2);   // 35.2 MB bf16 (K-padded)
  ushort_t* xlr = (ushort_t*)alloc((size_t)N_NODES * HC * 2);   // 130 MB bf16
  ushort_t* Wt  = (ushort_t*)alloc((size_t)HC * KP * 2);        // 0.9 MB bf16
  float* yl     = (float*)alloc((size_t)N_NODES * 10 * 4);
  int*   deg    = (int*)alloc((size_t)N_NODES * 4);
  int*   offs   = (int*)alloc((size_t)(N_NODES + 1) * 4);
  int*   cursor = (int*)alloc((size_t)N_NODES * 4);
  int*   csrs   = (int*)alloc((size_t)N_EDGES * 4);
  float* csrw   = (float*)alloc((size_t)N_EDGES * 4);
  float* Wlf    = (float*)alloc((size_t)FDIM * 10 * 4);
  float* red    = (float*)alloc(64);
  float* cvec   = (float*)alloc(64);

  k_init<<<(N_NODES + 255) / 256, 256, 0, stream>>>(deg, cursor, red);
  k_count<<<(N_EDGES + 255) / 256, 256, 0, stream>>>(dst, ew, deg, red);
  k_scan<<<1, 1024, 0, stream>>>(deg, offs);
  k_scatter<<<(N_EDGES + 255) / 256, 256, 0, stream>>>(src, dst, ew, offs, cursor, csrs, csrw);
  k_gcn<<<N_NODES, 64, 0, stream>>>(h, edge_num, offs, csrs, csrw,
                                    Wsum, bsum, Wmean, bmean, Wmax, bmax,
                                    Wne, bne, Wnem, bnem, x);
  k_wt<<<(HC * KP + 255) / 256, 256, 0, stream>>>(Wl, Wr, Wt);
  dim3 gg((HC + 127) / 128, (N_NODES + 127) / 128);   // bn fastest -> A-panel L2 reuse
  k_gemm_mfma<<<gg, 256, 0, stream>>>(x, Wt, xlr);
  k_wlf<<<(FDIM * 10 + 255) / 256, 256, 0, stream>>>(Wl, Wfc, Wlf);
  k_yl<<<(N_NODES * 64 + 255) / 256, 256, 0, stream>>>(x, Wlf, yl);
  k_cvec<<<1, 64, 0, stream>>>(b_att, Wfc, bfc, red, cvec);
  k_att<<<(N_NODES * 64 + 255) / 256, 256, 0, stream>>>(offs, csrs, csrw, xlr,
                                                        We, att, cvec, yl, out);
}

// Round 12
// 469.873 us; speedup vs baseline: 2.7892x; 1.1629x over previous
//
#include <hip/hip_runtime.h>
#include <hip/hip_bf16.h>
#include <math.h>

#define N_NODES 50000
#define N_EDGES 150000
#define FDIM 325
#define KP 352        // K padded to multiple of 32
#define HCP 1312      // padded xlr row: xl @ [0,650), pad, xr @ [656,1306), pad
#define XROFF 656
#define LDA 40        // LDS A/B tile row stride (ushorts)
#define LDC 136       // LDS C-staging row stride (ushorts, 272B: 16B-aligned, bank-spread)
#define NPAN 391      // M panels (50000/128)
#define NBJ 11        // N blocks  (1312/128 -> 10.25 -> 11)
#define SCAN_B 256
#define NBLK ((N_NODES + SCAN_B - 1) / SCAN_B)   // 196

typedef unsigned short ushort_t;
typedef __attribute__((ext_vector_type(8))) short short8v;
typedef __attribute__((ext_vector_type(4))) float f32x4;

__device__ __forceinline__ float bf2f(ushort_t u) {
  return __uint_as_float(((unsigned)u) << 16);
}
__device__ __forceinline__ ushort_t f2bf(float f) {
  __hip_bfloat16 h = __float2bfloat16(f);
  union { __hip_bfloat16 h; ushort_t u; } cv; cv.h = h;
  return cv.u;
}

// ---------------- init ----------------
__global__ void k_init(int* deg, int* cursor, float* red) {
  int i = blockIdx.x * blockDim.x + threadIdx.x;
  if (i < N_NODES) { deg[i] = 0; cursor[i] = 0; }
  if (i == 0) red[0] = 0.f;
}

// ---------------- degree count + edge-weight sum ----------------
__global__ void k_count(const int* __restrict__ dst, const float* __restrict__ ew,
                        int* deg, float* red) {
  int e = blockIdx.x * blockDim.x + threadIdx.x;
  float w = 0.f;
  if (e < N_EDGES) { atomicAdd(&deg[dst[e]], 1); w = ew[e]; }
  #pragma unroll
  for (int m = 32; m; m >>= 1) w += __shfl_xor(w, m);
  if ((threadIdx.x & 63) == 0) atomicAdd(red, w);
}

// ---------------- hierarchical exclusive scan deg -> offs ----------------
__global__ void k_scan1(const int* __restrict__ deg, int* offs, int* bsum) {
  __shared__ int buf[SCAN_B];
  int b = blockIdx.x, tid = threadIdx.x, i = b * SCAN_B + tid;
  int v = (i < N_NODES) ? deg[i] : 0;
  buf[tid] = v;
  __syncthreads();
  for (int o = 1; o < SCAN_B; o <<= 1) {
    int t = (tid >= o) ? buf[tid - o] : 0;
    __syncthreads();
    buf[tid] += t;
    __syncthreads();
  }
  if (i < N_NODES) offs[i + 1] = buf[tid];       // inclusive within block
  if (tid == SCAN_B - 1) bsum[b] = buf[tid];
}
__global__ void k_scan2(const int* __restrict__ bsum, int* bofs) {
  __shared__ int buf[256];
  int tid = threadIdx.x;
  int v = (tid < NBLK) ? bsum[tid] : 0;
  buf[tid] = v;
  __syncthreads();
  for (int o = 1; o < 256; o <<= 1) {
    int t = (tid >= o) ? buf[tid - o] : 0;
    __syncthreads();
    buf[tid] += t;
    __syncthreads();
  }
  if (tid < NBLK) bofs[tid] = buf[tid] - v;      // exclusive block offsets
}
__global__ void k_scan3(const int* __restrict__ bofs, int* offs) {
  int i = blockIdx.x * blockDim.x + threadIdx.x;
  if (i == 0) offs[0] = 0;
  if (i < N_NODES) offs[i + 1] += bofs[i / SCAN_B];
}

// ---------------- scatter edges to CSR (by dst) ----------------
__global__ void k_scatter(const int* __restrict__ src, const int* __restrict__ dst,
                          const float* __restrict__ ew, const int* __restrict__ offs,
                          int* cursor, int* csr_src, float* csr_w) {
  int e = blockIdx.x * blockDim.x + threadIdx.x;
  if (e >= N_EDGES) return;
  int d = dst[e];
  int p = offs[d] + atomicAdd(&cursor[d], 1);
  csr_src[p] = src[e];
  csr_w[p] = ew[e];
}

// ---------------- fused 5x GCNConv aggregation -> x [N,KP] bf16 (K-padded) ----------------
__global__ void __launch_bounds__(64) k_gcn(
    const float* __restrict__ h, const float* __restrict__ edge_num,
    const int* __restrict__ offs, const int* __restrict__ csr_src,
    const float* __restrict__ csr_w,
    const float* __restrict__ Wsum, const float* __restrict__ bsum,
    const float* __restrict__ Wmean, const float* __restrict__ bmean,
    const float* __restrict__ Wmax, const float* __restrict__ bmax,
    const float* __restrict__ Wne, const float* __restrict__ bne,
    const float* __restrict__ Wnem, const float* __restrict__ bnem,
    ushort_t* __restrict__ x) {
  int n = blockIdx.x;
  int t = threadIdx.x;
  float w0[5], w1[5], w2[5], w3[5], w4[5];
  #pragma unroll
  for (int k = 0; k < 5; ++k) {
    w0[k] = Wsum[k * 64 + t];
    w1[k] = Wmean[k * 64 + t];
    w2[k] = Wmax[k * 64 + t];
    w3[k] = Wne[k * 64 + t];
    w4[k] = Wnem[k * 64 + t];
  }
  float s_sum = 0.f, s_wmean = 0.f, s_max = -INFINITY, s_ne = 0.f, s_nem = -INFINITY;
  int beg = offs[n], end = offs[n + 1];
  for (int i = beg; i < end; ++i) {
    int s = csr_src[i];
    float w = csr_w[i];
    float hs[5];
    #pragma unroll
    for (int k = 0; k < 5; ++k) hs[k] = h[s * 5 + k];
    float v0 = 0, v1 = 0, v2 = 0, v3 = 0, v4 = 0;
    #pragma unroll
    for (int k = 0; k < 5; ++k) {
      v0 += hs[k] * w0[k]; v1 += hs[k] * w1[k]; v2 += hs[k] * w2[k];
      v3 += hs[k] * w3[k]; v4 += hs[k] * w4[k];
    }
    s_sum += w * v0;
    s_wmean += w * v1;
    s_max = fmaxf(s_max, w * v2);
    s_ne += v3;
    s_nem = fmaxf(s_nem, v4);
  }
  int dg = end - beg;
  float inv = 1.f / (float)(dg > 0 ? dg : 1);
  ushort_t* xr = x + (size_t)n * KP;
  xr[t]       = f2bf(s_sum + bsum[t]);
  xr[64 + t]  = f2bf(s_wmean * inv + bmean[t]);
  xr[128 + t] = f2bf((dg ? s_max : 0.f) + bmax[t]);
  xr[192 + t] = f2bf(s_ne + bne[t]);
  xr[256 + t] = f2bf((dg ? s_nem : 0.f) + bnem[t]);
  if (t < 5) xr[320 + t] = f2bf(edge_num[n * 5 + t]);
  if (t < KP - FDIM) xr[FDIM + t] = 0;   // zero-pad K 325..351
}

// ---------------- Wt[HCP][KP] bf16: [Wl | pad | Wr | pad]^T, k-contiguous ----------------
__global__ void k_wt(const float* __restrict__ Wl, const float* __restrict__ Wr,
                     ushort_t* __restrict__ Wt) {
  int t = blockIdx.x * blockDim.x + threadIdx.x;
  if (t >= HCP * KP) return;
  int n = t / KP, k = t % KP;
  float v = 0.f;
  if (k < FDIM) {
    if (n < 650) v = Wl[(size_t)k * 650 + n];
    else if (n >= XROFF && n < XROFF + 650) v = Wr[(size_t)k * 650 + (n - XROFF)];
  }
  Wt[t] = f2bf(v);
}

// ---------------- MFMA GEMM: xlr[N,HCP] (bf16) = x[N,325] @ Wt^T ----------------
// 1D grid, XCD-aware decode: the 11 bn-blocks of one A-panel get linear ids
// congruent mod 8 -> same XCD L2 -> A-panel fetched once. C staged through LDS
// and written as 16B full-line stores (kills write-allocate RMW fetch).
__global__ void __launch_bounds__(256) k_gemm_mfma(
    const ushort_t* __restrict__ x, const ushort_t* __restrict__ Wt,
    ushort_t* __restrict__ xlr) {
  __shared__ ushort_t smem[128 * LDA * 2];   // As | Bs ; reused as Cs in epilogue
  ushort_t* As = smem;
  ushort_t* Bs = smem + 128 * LDA;
  ushort_t* Cs = smem;                       // 64 x LDC <= 2*128*LDA

  // ---- XCD-aware block decode ----
  int L = blockIdx.x;
  int panel, jb;
  if (L < 4224) {            // 48 chunks x (8 panels x 11 jb)
    int chunk = L / 88, g = L % 88;
    panel = chunk * 8 + (g & 7);
    jb = g >> 3;
  } else {                   // remainder: 7 panels x 11 jb
    int g = L - 4224;
    panel = 384 + g % 7;
    jb = g / 7;
  }
  int bm = panel * 128, bn = jb * 128;

  int tid = threadIdx.x;
  int lane = tid & 63, wave = tid >> 6;
  int wr = wave >> 1, wc = wave & 1;         // 2x2 waves, each owns 64x64 of C
  f32x4 acc[4][4] = {};
  for (int k0 = 0; k0 < KP; k0 += 32) {
    #pragma unroll
    for (int it = 0; it < 2; ++it) {
      int idx = tid + it * 256;              // 0..511
      int row = idx >> 2, kc = (idx & 3) << 3;
      int gm = bm + row;
      float4 av = make_float4(0.f, 0.f, 0.f, 0.f);
      if (gm < N_NODES) av = *(const float4*)&x[(size_t)gm * KP + k0 + kc];
      *(float4*)&As[row * LDA + kc] = av;
      int gn = bn + row;
      float4 bv = make_float4(0.f, 0.f, 0.f, 0.f);
      if (gn < HCP) bv = *(const float4*)&Wt[(size_t)gn * KP + k0 + kc];
      *(float4*)&Bs[row * LDA + kc] = bv;
    }
    __syncthreads();
    int koff = (lane >> 4) << 3;             // 0,8,16,24
    int ar = (wr << 6) + (lane & 15);
    int br = (wc << 6) + (lane & 15);
    short8v a[4], b[4];
    #pragma unroll
    for (int i = 0; i < 4; ++i) a[i] = *(const short8v*)&As[(ar + i * 16) * LDA + koff];
    #pragma unroll
    for (int j = 0; j < 4; ++j) b[j] = *(const short8v*)&Bs[(br + j * 16) * LDA + koff];
    #pragma unroll
    for (int i = 0; i < 4; ++i)
      #pragma unroll
      for (int j = 0; j < 4; ++j)
        acc[i][j] = __builtin_amdgcn_mfma_f32_16x16x32_bf16(a[i], b[j], acc[i][j], 0, 0, 0);
    __syncthreads();
  }
  // ---- epilogue: stage 64-row halves in LDS, write out coalesced 16B chunks ----
  // C/D frag layout: col = lane&15, local row = (lane>>4)*4 + reg
  #pragma unroll
  for (int half = 0; half < 2; ++half) {
    if (wr == half) {
      int lr0 = ((lane >> 4) << 2);
      int c0 = (wc << 6) + (lane & 15);
      #pragma unroll
      for (int i = 0; i < 4; ++i)
        #pragma unroll
        for (int j = 0; j < 4; ++j)
          #pragma unroll
          for (int r = 0; r < 4; ++r)
            Cs[(lr0 + i * 16 + r) * LDC + c0 + j * 16] = f2bf(acc[i][j][r]);
    }
    __syncthreads();
    #pragma unroll
    for (int it = 0; it < 4; ++it) {
      int idx = tid + it * 256;              // 0..1023 = 64 rows x 16 chunks
      int lr = idx >> 4, cc = idx & 15;
      int row = bm + half * 64 + lr;
      int col = bn + cc * 8;
      if (row < N_NODES && col < HCP) {
        short8v v = *(const short8v*)&Cs[lr * LDC + cc * 8];
        *(short8v*)&xlr[(size_t)row * HCP + col] = v;
      }
    }
    __syncthreads();
  }
}

// ---------------- Wlf[325,10] = per-head Wl @ Wfc fusion ----------------
__global__ void k_wlf(const float* __restrict__ Wl, const float* __restrict__ Wfc,
                      float* __restrict__ Wlf) {
  int t = blockIdx.x * blockDim.x + threadIdx.x;
  if (t >= FDIM * 10) return;
  int cp = t / 10, o = t % 10;
  int hh = o / 5, j = o % 5;
  float s = 0.f;
  for (int c = 0; c < 325; ++c) s += Wl[(size_t)cp * 650 + hh * 325 + c] * Wfc[c * 5 + j];
  Wlf[cp * 10 + o] = s;
}

// ---------------- yl[N,2,5] = x @ Wlf (f32 accumulate) ----------------
__global__ void k_yl(const ushort_t* __restrict__ x, const float* __restrict__ Wlf,
                     float* __restrict__ yl) {
  int wid = (blockIdx.x * blockDim.x + threadIdx.x) >> 6;
  int lane = threadIdx.x & 63;
  if (wid >= N_NODES) return;
  const ushort_t* row = x + (size_t)wid * KP;
  float p[10] = {};
  for (int c = lane; c < FDIM; c += 64) {
    float v = bf2f(row[c]);
    const float* wr = Wlf + c * 10;
    #pragma unroll
    for (int j = 0; j < 10; ++j) p[j] += v * wr[j];
  }
  #pragma unroll
  for (int j = 0; j < 10; ++j)
    #pragma unroll
    for (int m = 32; m; m >>= 1) p[j] += __shfl_xor(p[j], m);
  if (lane == 0) {
    #pragma unroll
    for (int j = 0; j < 10; ++j) yl[(size_t)wid * 10 + j] = p[j];
  }
}

// ---------------- cvec[j] = b_att @ W_fc1 + b_fc1 ; cvec[5] = mean(ew) ----------------
__global__ void k_cvec(const float* __restrict__ b_att, const float* __restrict__ Wfc,
                       const float* __restrict__ b_fc1, const float* __restrict__ red,
                       float* __restrict__ cvec) {
  int j = threadIdx.x;
  if (j == 5) cvec[5] = red[0] / (float)N_EDGES;
  if (j < 5) {
    float s = b_fc1[j];
    for (int c = 0; c < 325; ++c) s += b_att[c] * Wfc[c * 5 + j];
    cvec[j] = s;
  }
}

// ---------------- fused GATv2 attention (vectorized): per-dst online softmax ----------------
// lane slot j0: c = lane*8+e (0..511); slot j1 (lane<18): c = 512+lane*8+e (512..655, att=0 pad)
__global__ void __launch_bounds__(256) k_att(
    const int* __restrict__ offs, const int* __restrict__ csrs,
    const float* __restrict__ csrw, const ushort_t* __restrict__ xlr,
    const float* __restrict__ We, const float* __restrict__ att,
    const float* __restrict__ cvec, const float* __restrict__ yl,
    float* __restrict__ out) {
  int d = (blockIdx.x * blockDim.x + threadIdx.x) >> 6;
  int lane = threadIdx.x & 63;
  if (d >= N_NODES) return;
  float xd0[8], xd1[8], We0[8], We1[8], at0[8], at1[8];
  const ushort_t* xd = xlr + (size_t)d * HCP + XROFF;
  {
    short8v v = *(const short8v*)&xd[lane * 8];
    int c0 = lane * 8;
    #pragma unroll
    for (int e = 0; e < 8; ++e) {
      xd0[e] = bf2f((ushort_t)v[e]);
      We0[e] = We[c0 + e];
      at0[e] = att[c0 + e];
    }
  }
  if (lane < 18) {
    short8v v = *(const short8v*)&xd[512 + lane * 8];
    int c0 = 512 + lane * 8;
    #pragma unroll
    for (int e = 0; e < 8; ++e) {
      bool ok = (c0 + e) < 650;
      xd1[e] = bf2f((ushort_t)v[e]);
      We1[e] = ok ? We[c0 + e] : 0.f;
      at1[e] = ok ? att[c0 + e] : 0.f;
    }
  }
  float meanw = cvec[5];
  int beg = offs[d], end = offs[d + 1];
  float m0 = -INFINITY, m1 = -INFINITY, s0 = 0.f, s1 = 0.f;
  float oj = 0.f;   // lanes 0..9: o_j (j<5 head0 dims, j>=5 head1 dims)
  for (int i = beg; i <= end; ++i) {   // i == end -> self-loop
    int s; float ea;
    if (i < end) { s = csrs[i]; ea = csrw[i]; }
    else { s = d; ea = meanw; }
    const ushort_t* xs = xlr + (size_t)s * HCP;
    float p0 = 0.f, p1 = 0.f;
    {
      short8v v = *(const short8v*)&xs[lane * 8];
      int c0 = lane * 8;
      #pragma unroll
      for (int e = 0; e < 8; ++e) {
        float vv = bf2f((ushort_t)v[e]) + xd0[e] + ea * We0[e];
        vv = (vv > 0.f) ? vv : 0.2f * vv;
        float t = vv * at0[e];
        if (c0 + e < 325) p0 += t; else p1 += t;
      }
    }
    if (lane < 18) {
      short8v v = *(const short8v*)&xs[512 + lane * 8];
      #pragma unroll
      for (int e = 0; e < 8; ++e) {
        float vv = bf2f((ushort_t)v[e]) + xd1[e] + ea * We1[e];
        vv = (vv > 0.f) ? vv : 0.2f * vv;
        p1 += vv * at1[e];   // all c >= 512 -> head1 (pads masked by at1=0)
      }
    }
    #pragma unroll
    for (int m = 32; m; m >>= 1) { p0 += __shfl_xor(p0, m); p1 += __shfl_xor(p1, m); }
    float nm0 = fmaxf(m0, p0), nm1 = fmaxf(m1, p1);
    float r0 = __expf(m0 - nm0), r1 = __expf(m1 - nm1);  // first iter: exp(-inf)=0
    float e0 = __expf(p0 - nm0), e1 = __expf(p1 - nm1);
    s0 = s0 * r0 + e0; s1 = s1 * r1 + e1;
    m0 = nm0; m1 = nm1;
    if (lane < 10) {
      float yv = yl[(size_t)s * 10 + lane];
      float r = (lane < 5) ? r0 : r1;
      float e = (lane < 5) ? e0 : e1;
      oj = oj * r + e * yv;
    }
  }
  float on = oj / ((lane < 5) ? s0 : s1);
  float other = __shfl(on, lane + 5);
  if (lane < 5) {
    int dg = end - beg;
    out[(size_t)d * 5 + lane] = (on + other) / (2.f * (float)(dg + 1)) + cvec[lane];
  }
}

extern "C" void kernel_launch(void* const* d_in, const int* in_sizes, int n_in,
                              void* d_out, int out_size, void* d_ws, size_t ws_size,
                              hipStream_t stream) {
  (void)in_sizes; (void)n_in; (void)out_size; (void)ws_size;
  const float* h        = (const float*)d_in[0];
  const float* edge_num = (const float*)d_in[1];
  const int*   eidx     = (const int*)d_in[2];
  const float* ew       = (const float*)d_in[3];
  const float* Wsum  = (const float*)d_in[4];  const float* bsum_  = (const float*)d_in[5];
  const float* Wmean = (const float*)d_in[6];  const float* bmean = (const float*)d_in[7];
  const float* Wmax  = (const float*)d_in[8];  const float* bmax  = (const float*)d_in[9];
  const float* Wne   = (const float*)d_in[10]; const float* bne   = (const float*)d_in[11];
  const float* Wnem  = (const float*)d_in[12]; const float* bnem  = (const float*)d_in[13];
  const float* Wl    = (const float*)d_in[14]; const float* Wr    = (const float*)d_in[15];
  const float* We    = (const float*)d_in[16]; const float* att   = (const float*)d_in[17];
  const float* b_att = (const float*)d_in[18];
  const float* Wfc   = (const float*)d_in[19]; const float* bfc   = (const float*)d_in[20];
  const int* src = eidx;
  const int* dst = eidx + N_EDGES;
  float* out = (float*)d_out;

  // workspace layout (~172 MB peak)
  char* p = (char*)d_ws;
  size_t off = 0;
  auto alloc = [&](size_t bytes) { char* r = p + off; off = (off + bytes + 255) & ~(size_t)255; return r; };
  ushort_t* x   = (ushort_t*)alloc((size_t)N_NODES * KP * 2);    // 35.2 MB bf16
  ushort_t* xlr = (ushort_t*)alloc((size_t)N_NODES * HCP * 2);   // 131.2 MB bf16 (padded layout)
  ushort_t* Wt  = (ushort_t*)alloc((size_t)HCP * KP * 2);        // 0.92 MB bf16
  float* yl     = (float*)alloc((size_t)N_NODES * 10 * 4);
  int*   deg    = (int*)alloc((size_t)N_NODES * 4);
  int*   offs   = (int*)alloc((size_t)(N_NODES + 1) * 4);
  int*   cursor = (int*)alloc((size_t)N_NODES * 4);
  int*   csrs   = (int*)alloc((size_t)N_EDGES * 4);
  float* csrw   = (float*)alloc((size_t)N_EDGES * 4);
  int*   bsum   = (int*)alloc((size_t)NBLK * 4);
  int*   bofs   = (int*)alloc((size_t)NBLK * 4);
  float* Wlf    = (float*)alloc((size_t)FDIM * 10 * 4);
  float* red    = (float*)alloc(64);
  float* cvec   = (float*)alloc(64);

  k_init<<<(N_NODES + 255) / 256, 256, 0, stream>>>(deg, cursor, red);
  k_count<<<(N_EDGES + 255) / 256, 256, 0, stream>>>(dst, ew, deg, red);
  k_scan1<<<NBLK, SCAN_B, 0, stream>>>(deg, offs, bsum);
  k_scan2<<<1, 256, 0, stream>>>(bsum, bofs);
  k_scan3<<<NBLK, SCAN_B, 0, stream>>>(bofs, offs);
  k_scatter<<<(N_EDGES + 255) / 256, 256, 0, stream>>>(src, dst, ew, offs, cursor, csrs, csrw);
  k_gcn<<<N_NODES, 64, 0, stream>>>(h, edge_num, offs, csrs, csrw,
                                    Wsum, bsum_, Wmean, bmean, Wmax, bmax,
                                    Wne, bne, Wnem, bnem, x);
  k_wt<<<(HCP * KP + 255) / 256, 256, 0, stream>>>(Wl, Wr, Wt);
  k_gemm_mfma<<<NPAN * NBJ, 256, 0, stream>>>(x, Wt, xlr);   // 4301 blocks, XCD-decoded
  k_wlf<<<(FDIM * 10 + 255) / 256, 256, 0, stream>>>(Wl, Wfc, Wlf);
  k_yl<<<(N_NODES * 64 + 255) / 256, 256, 0, stream>>>(x, Wlf, yl);
  k_cvec<<<1, 64, 0, stream>>>(b_att, Wfc, bfc, red, cvec);
  k_att<<<(N_NODES * 64 + 255) / 256, 256, 0, stream>>>(offs, csrs, csrw, xlr,
                                                        We, att, cvec, yl, out);
}

// Round 13
// 464.130 us; speedup vs baseline: 2.8237x; 1.0124x over previous
//
#include <hip/hip_runtime.h>
#include <hip/hip_bf16.h>
#include <math.h>

#define N_NODES 50000
#define N_EDGES 150000
#define FDIM 325
#define KP 352        // K padded to multiple of 32
#define HCP 1312      // padded xlr row: xl @ [0,650), pad, xr @ [656,1306), pad
#define XROFF 656
#define LDA 40        // LDS A/B tile row stride (ushorts)
#define LDC 136       // LDS C-staging row stride (ushorts)
#define NPAN 391      // M panels (50000/128)
#define NBJ 11        // N blocks (1312/128)
#define SCAN_B 256
#define NBLK ((N_NODES + SCAN_B - 1) / SCAN_B)   // 196

typedef unsigned short ushort_t;
typedef __attribute__((ext_vector_type(8))) short short8v;
typedef __attribute__((ext_vector_type(4))) float f32x4;

__device__ __forceinline__ float bf2f(ushort_t u) {
  return __uint_as_float(((unsigned)u) << 16);
}
__device__ __forceinline__ ushort_t f2bf(float f) {
  __hip_bfloat16 h = __float2bfloat16(f);
  union { __hip_bfloat16 h; ushort_t u; } cv; cv.h = h;
  return cv.u;
}

// ---------------- init ----------------
__global__ void k_init(int* deg, int* cursor, float* red) {
  int i = blockIdx.x * blockDim.x + threadIdx.x;
  if (i < N_NODES) { deg[i] = 0; cursor[i] = 0; }
  if (i == 0) red[0] = 0.f;
}

// ---------------- degree count + edge-weight sum ----------------
__global__ void k_count(const int* __restrict__ dst, const float* __restrict__ ew,
                        int* deg, float* red) {
  int e = blockIdx.x * blockDim.x + threadIdx.x;
  float w = 0.f;
  if (e < N_EDGES) { atomicAdd(&deg[dst[e]], 1); w = ew[e]; }
  #pragma unroll
  for (int m = 32; m; m >>= 1) w += __shfl_xor(w, m);
  if ((threadIdx.x & 63) == 0) atomicAdd(red, w);
}

// ---------------- hierarchical exclusive scan deg -> offs ----------------
__global__ void k_scan1(const int* __restrict__ deg, int* offs, int* bsum) {
  __shared__ int buf[SCAN_B];
  int b = blockIdx.x, tid = threadIdx.x, i = b * SCAN_B + tid;
  int v = (i < N_NODES) ? deg[i] : 0;
  buf[tid] = v;
  __syncthreads();
  for (int o = 1; o < SCAN_B; o <<= 1) {
    int t = (tid >= o) ? buf[tid - o] : 0;
    __syncthreads();
    buf[tid] += t;
    __syncthreads();
  }
  if (i < N_NODES) offs[i + 1] = buf[tid];       // inclusive within block
  if (tid == SCAN_B - 1) bsum[b] = buf[tid];
}
__global__ void k_scan2(const int* __restrict__ bsum, int* bofs) {
  __shared__ int buf[256];
  int tid = threadIdx.x;
  int v = (tid < NBLK) ? bsum[tid] : 0;
  buf[tid] = v;
  __syncthreads();
  for (int o = 1; o < 256; o <<= 1) {
    int t = (tid >= o) ? buf[tid - o] : 0;
    __syncthreads();
    buf[tid] += t;
    __syncthreads();
  }
  if (tid < NBLK) bofs[tid] = buf[tid] - v;      // exclusive block offsets
}
__global__ void k_scan3(const int* __restrict__ bofs, int* offs) {
  int i = blockIdx.x * blockDim.x + threadIdx.x;
  if (i == 0) offs[0] = 0;
  if (i < N_NODES) offs[i + 1] += bofs[i / SCAN_B];
}

// ---------------- scatter edges to CSR (by dst) ----------------
__global__ void k_scatter(const int* __restrict__ src, const int* __restrict__ dst,
                          const float* __restrict__ ew, const int* __restrict__ offs,
                          int* cursor, int* csr_src, float* csr_w) {
  int e = blockIdx.x * blockDim.x + threadIdx.x;
  if (e >= N_EDGES) return;
  int d = dst[e];
  int p = offs[d] + atomicAdd(&cursor[d], 1);
  csr_src[p] = src[e];
  csr_w[p] = ew[e];
}

// ---------------- fused 5x GCNConv aggregation -> x [N,KP] bf16 (K-padded) ----------------
// software-pipelined gather: edge i+1's (src,w,h-row) loads issue before edge i's math
__global__ void __launch_bounds__(64) k_gcn(
    const float* __restrict__ h, const float* __restrict__ edge_num,
    const int* __restrict__ offs, const int* __restrict__ csr_src,
    const float* __restrict__ csr_w,
    const float* __restrict__ Wsum, const float* __restrict__ bsum,
    const float* __restrict__ Wmean, const float* __restrict__ bmean,
    const float* __restrict__ Wmax, const float* __restrict__ bmax,
    const float* __restrict__ Wne, const float* __restrict__ bne,
    const float* __restrict__ Wnem, const float* __restrict__ bnem,
    ushort_t* __restrict__ x) {
  int n = blockIdx.x;
  int t = threadIdx.x;
  float w0[5], w1[5], w2[5], w3[5], w4[5];
  #pragma unroll
  for (int k = 0; k < 5; ++k) {
    w0[k] = Wsum[k * 64 + t];
    w1[k] = Wmean[k * 64 + t];
    w2[k] = Wmax[k * 64 + t];
    w3[k] = Wne[k * 64 + t];
    w4[k] = Wnem[k * 64 + t];
  }
  float s_sum = 0.f, s_wmean = 0.f, s_max = -INFINITY, s_ne = 0.f, s_nem = -INFINITY;
  int beg = offs[n], end = offs[n + 1];
  float wcur = 0.f, hcur[5];
  if (beg < end) {
    int s = csr_src[beg];
    wcur = csr_w[beg];
    #pragma unroll
    for (int k = 0; k < 5; ++k) hcur[k] = h[s * 5 + k];
  }
  for (int i = beg; i < end; ++i) {
    float wnxt = 0.f, hnxt[5];
    if (i + 1 < end) {
      int s = csr_src[i + 1];
      wnxt = csr_w[i + 1];
      #pragma unroll
      for (int k = 0; k < 5; ++k) hnxt[k] = h[s * 5 + k];
    }
    float v0 = 0, v1 = 0, v2 = 0, v3 = 0, v4 = 0;
    #pragma unroll
    for (int k = 0; k < 5; ++k) {
      v0 += hcur[k] * w0[k]; v1 += hcur[k] * w1[k]; v2 += hcur[k] * w2[k];
      v3 += hcur[k] * w3[k]; v4 += hcur[k] * w4[k];
    }
    s_sum += wcur * v0;
    s_wmean += wcur * v1;
    s_max = fmaxf(s_max, wcur * v2);
    s_ne += v3;
    s_nem = fmaxf(s_nem, v4);
    wcur = wnxt;
    #pragma unroll
    for (int k = 0; k < 5; ++k) hcur[k] = hnxt[k];
  }
  int dg = end - beg;
  float inv = 1.f / (float)(dg > 0 ? dg : 1);
  ushort_t* xr = x + (size_t)n * KP;
  xr[t]       = f2bf(s_sum + bsum[t]);
  xr[64 + t]  = f2bf(s_wmean * inv + bmean[t]);
  xr[128 + t] = f2bf((dg ? s_max : 0.f) + bmax[t]);
  xr[192 + t] = f2bf(s_ne + bne[t]);
  xr[256 + t] = f2bf((dg ? s_nem : 0.f) + bnem[t]);
  if (t < 5) xr[320 + t] = f2bf(edge_num[n * 5 + t]);
  if (t < KP - FDIM) xr[FDIM + t] = 0;   // zero-pad K 325..351
}

// ---------------- Wt[HCP][KP] bf16: [Wl | pad | Wr | pad]^T, k-contiguous ----------------
__global__ void k_wt(const float* __restrict__ Wl, const float* __restrict__ Wr,
                     ushort_t* __restrict__ Wt) {
  int t = blockIdx.x * blockDim.x + threadIdx.x;
  if (t >= HCP * KP) return;
  int n = t / KP, k = t % KP;
  float v = 0.f;
  if (k < FDIM) {
    if (n < 650) v = Wl[(size_t)k * 650 + n];
    else if (n >= XROFF && n < XROFF + 650) v = Wr[(size_t)k * 650 + (n - XROFF)];
  }
  Wt[t] = f2bf(v);
}

// ---------------- MFMA GEMM: xlr[N,HCP] (bf16) = x[N,325] @ Wt^T ----------------
__global__ void __launch_bounds__(256) k_gemm_mfma(
    const ushort_t* __restrict__ x, const ushort_t* __restrict__ Wt,
    ushort_t* __restrict__ xlr) {
  __shared__ ushort_t smem[128 * LDA * 2];   // As | Bs ; reused as Cs in epilogue
  ushort_t* As = smem;
  ushort_t* Bs = smem + 128 * LDA;
  ushort_t* Cs = smem;                       // 64 x LDC <= 2*128*LDA

  // ---- XCD-aware block decode ----
  int L = blockIdx.x;
  int panel, jb;
  if (L < 4224) {            // 48 chunks x (8 panels x 11 jb)
    int chunk = L / 88, g = L % 88;
    panel = chunk * 8 + (g & 7);
    jb = g >> 3;
  } else {                   // remainder: 7 panels x 11 jb
    int g = L - 4224;
    panel = 384 + g % 7;
    jb = g / 7;
  }
  int bm = panel * 128, bn = jb * 128;

  int tid = threadIdx.x;
  int lane = tid & 63, wave = tid >> 6;
  int wr = wave >> 1, wc = wave & 1;         // 2x2 waves, each owns 64x64 of C
  f32x4 acc[4][4] = {};
  for (int k0 = 0; k0 < KP; k0 += 32) {
    #pragma unroll
    for (int it = 0; it < 2; ++it) {
      int idx = tid + it * 256;              // 0..511
      int row = idx >> 2, kc = (idx & 3) << 3;
      int gm = bm + row;
      float4 av = make_float4(0.f, 0.f, 0.f, 0.f);
      if (gm < N_NODES) av = *(const float4*)&x[(size_t)gm * KP + k0 + kc];
      *(float4*)&As[row * LDA + kc] = av;
      int gn = bn + row;
      float4 bv = make_float4(0.f, 0.f, 0.f, 0.f);
      if (gn < HCP) bv = *(const float4*)&Wt[(size_t)gn * KP + k0 + kc];
      *(float4*)&Bs[row * LDA + kc] = bv;
    }
    __syncthreads();
    int koff = (lane >> 4) << 3;             // 0,8,16,24
    int ar = (wr << 6) + (lane & 15);
    int br = (wc << 6) + (lane & 15);
    short8v a[4], b[4];
    #pragma unroll
    for (int i = 0; i < 4; ++i) a[i] = *(const short8v*)&As[(ar + i * 16) * LDA + koff];
    #pragma unroll
    for (int j = 0; j < 4; ++j) b[j] = *(const short8v*)&Bs[(br + j * 16) * LDA + koff];
    #pragma unroll
    for (int i = 0; i < 4; ++i)
      #pragma unroll
      for (int j = 0; j < 4; ++j)
        acc[i][j] = __builtin_amdgcn_mfma_f32_16x16x32_bf16(a[i], b[j], acc[i][j], 0, 0, 0);
    __syncthreads();
  }
  // ---- epilogue: stage 64-row halves in LDS, write out coalesced 16B chunks ----
  #pragma unroll
  for (int half = 0; half < 2; ++half) {
    if (wr == half) {
      int lr0 = ((lane >> 4) << 2);
      int c0 = (wc << 6) + (lane & 15);
      #pragma unroll
      for (int i = 0; i < 4; ++i)
        #pragma unroll
        for (int j = 0; j < 4; ++j)
          #pragma unroll
          for (int r = 0; r < 4; ++r)
            Cs[(lr0 + i * 16 + r) * LDC + c0 + j * 16] = f2bf(acc[i][j][r]);
    }
    __syncthreads();
    #pragma unroll
    for (int it = 0; it < 4; ++it) {
      int idx = tid + it * 256;              // 0..1023 = 64 rows x 16 chunks
      int lr = idx >> 4, cc = idx & 15;
      int row = bm + half * 64 + lr;
      int col = bn + cc * 8;
      if (row < N_NODES && col < HCP) {
        short8v v = *(const short8v*)&Cs[lr * LDC + cc * 8];
        *(short8v*)&xlr[(size_t)row * HCP + col] = v;
      }
    }
    __syncthreads();
  }
}

// ---------------- Wlf[325,10] = per-head Wl @ Wfc fusion ----------------
__global__ void k_wlf(const float* __restrict__ Wl, const float* __restrict__ Wfc,
                      float* __restrict__ Wlf) {
  int t = blockIdx.x * blockDim.x + threadIdx.x;
  if (t >= FDIM * 10) return;
  int cp = t / 10, o = t % 10;
  int hh = o / 5, j = o % 5;
  float s = 0.f;
  for (int c = 0; c < 325; ++c) s += Wl[(size_t)cp * 650 + hh * 325 + c] * Wfc[c * 5 + j];
  Wlf[cp * 10 + o] = s;
}

// ---------------- yl[N,2,5] = x @ Wlf (f32 accumulate) ----------------
__global__ void k_yl(const ushort_t* __restrict__ x, const float* __restrict__ Wlf,
                     float* __restrict__ yl) {
  int wid = (blockIdx.x * blockDim.x + threadIdx.x) >> 6;
  int lane = threadIdx.x & 63;
  if (wid >= N_NODES) return;
  const ushort_t* row = x + (size_t)wid * KP;
  float p[10] = {};
  for (int c = lane; c < FDIM; c += 64) {
    float v = bf2f(row[c]);
    const float* wr = Wlf + c * 10;
    #pragma unroll
    for (int j = 0; j < 10; ++j) p[j] += v * wr[j];
  }
  #pragma unroll
  for (int j = 0; j < 10; ++j)
    #pragma unroll
    for (int m = 32; m; m >>= 1) p[j] += __shfl_xor(p[j], m);
  if (lane == 0) {
    #pragma unroll
    for (int j = 0; j < 10; ++j) yl[(size_t)wid * 10 + j] = p[j];
  }
}

// ---------------- cvec[j] = b_att @ W_fc1 + b_fc1 ; cvec[5] = mean(ew) ----------------
__global__ void k_cvec(const float* __restrict__ b_att, const float* __restrict__ Wfc,
                       const float* __restrict__ b_fc1, const float* __restrict__ red,
                       float* __restrict__ cvec) {
  int j = threadIdx.x;
  if (j == 5) cvec[5] = red[0] / (float)N_EDGES;
  if (j < 5) {
    float s = b_fc1[j];
    for (int c = 0; c < 325; ++c) s += b_att[c] * Wfc[c * 5 + j];
    cvec[j] = s;
  }
}

// ---------------- fused GATv2 attention: software-pipelined online softmax ----------------
// edge i+1's loads (csr, xs vectors, yl) issue before edge i's reduce -> load
// latency hides under VALU work (the chain was serial; VALUBusy 55% -> target 75%)
__global__ void __launch_bounds__(256) k_att(
    const int* __restrict__ offs, const int* __restrict__ csrs,
    const float* __restrict__ csrw, const ushort_t* __restrict__ xlr,
    const float* __restrict__ We, const float* __restrict__ att,
    const float* __restrict__ cvec, const float* __restrict__ yl,
    float* __restrict__ out) {
  int d = (blockIdx.x * blockDim.x + threadIdx.x) >> 6;
  int lane = threadIdx.x & 63;
  if (d >= N_NODES) return;
  float xd0[8], xd1[8], We0[8], We1[8], at0[8], at1[8];
  const ushort_t* xd = xlr + (size_t)d * HCP + XROFF;
  {
    short8v v = *(const short8v*)&xd[lane * 8];
    int c0 = lane * 8;
    #pragma unroll
    for (int e = 0; e < 8; ++e) {
      xd0[e] = bf2f((ushort_t)v[e]);
      We0[e] = We[c0 + e];
      at0[e] = att[c0 + e];
    }
  }
  if (lane < 18) {
    short8v v = *(const short8v*)&xd[512 + lane * 8];
    int c0 = 512 + lane * 8;
    #pragma unroll
    for (int e = 0; e < 8; ++e) {
      bool ok = (c0 + e) < 650;
      xd1[e] = bf2f((ushort_t)v[e]);
      We1[e] = ok ? We[c0 + e] : 0.f;
      at1[e] = ok ? att[c0 + e] : 0.f;
    }
  }
  float meanw = cvec[5];
  int beg = offs[d], end = offs[d + 1];
  float m0 = -INFINITY, m1 = -INFINITY, s0 = 0.f, s1 = 0.f;
  float oj = 0.f;   // lanes 0..9: o_j (j<5 head0 dims, j>=5 head1 dims)

  // prologue: load edge `beg` (or the self-loop if degree==0)
  float ea_c, yv_c = 0.f;
  short8v v0_c, v1_c;
  {
    int s;
    if (beg < end) { s = csrs[beg]; ea_c = csrw[beg]; }
    else { s = d; ea_c = meanw; }
    const ushort_t* xs = xlr + (size_t)s * HCP;
    v0_c = *(const short8v*)&xs[lane * 8];
    if (lane < 18) v1_c = *(const short8v*)&xs[512 + lane * 8];
    if (lane < 10) yv_c = yl[(size_t)s * 10 + lane];
  }
  for (int i = beg; i <= end; ++i) {
    // ---- prefetch edge i+1 (issues loads; compiler keeps them in flight) ----
    float ea_n = 0.f, yv_n = 0.f;
    short8v v0_n, v1_n;
    bool have_next = (i < end);
    if (have_next) {
      int s;
      if (i + 1 < end) { s = csrs[i + 1]; ea_n = csrw[i + 1]; }
      else { s = d; ea_n = meanw; }
      const ushort_t* xs = xlr + (size_t)s * HCP;
      v0_n = *(const short8v*)&xs[lane * 8];
      if (lane < 18) v1_n = *(const short8v*)&xs[512 + lane * 8];
      if (lane < 10) yv_n = yl[(size_t)s * 10 + lane];
    }
    // ---- compute with current edge ----
    float p0 = 0.f, p1 = 0.f;
    {
      int c0 = lane * 8;
      #pragma unroll
      for (int e = 0; e < 8; ++e) {
        float vv = bf2f((ushort_t)v0_c[e]) + xd0[e] + ea_c * We0[e];
        vv = (vv > 0.f) ? vv : 0.2f * vv;
        float t = vv * at0[e];
        if (c0 + e < 325) p0 += t; else p1 += t;
      }
    }
    if (lane < 18) {
      #pragma unroll
      for (int e = 0; e < 8; ++e) {
        float vv = bf2f((ushort_t)v1_c[e]) + xd1[e] + ea_c * We1[e];
        vv = (vv > 0.f) ? vv : 0.2f * vv;
        p1 += vv * at1[e];   // pads masked by at1=0
      }
    }
    #pragma unroll
    for (int m = 32; m; m >>= 1) { p0 += __shfl_xor(p0, m); p1 += __shfl_xor(p1, m); }
    float nm0 = fmaxf(m0, p0), nm1 = fmaxf(m1, p1);
    float r0 = __expf(m0 - nm0), r1 = __expf(m1 - nm1);  // first iter: exp(-inf)=0
    float e0 = __expf(p0 - nm0), e1 = __expf(p1 - nm1);
    s0 = s0 * r0 + e0; s1 = s1 * r1 + e1;
    m0 = nm0; m1 = nm1;
    if (lane < 10) {
      float r = (lane < 5) ? r0 : r1;
      float e = (lane < 5) ? e0 : e1;
      oj = oj * r + e * yv_c;
    }
    // ---- rotate pipeline ----
    if (have_next) { ea_c = ea_n; yv_c = yv_n; v0_c = v0_n; v1_c = v1_n; }
  }
  float on = oj / ((lane < 5) ? s0 : s1);
  float other = __shfl(on, lane + 5);
  if (lane < 5) {
    int dg = end - beg;
    out[(size_t)d * 5 + lane] = (on + other) / (2.f * (float)(dg + 1)) + cvec[lane];
  }
}

extern "C" void kernel_launch(void* const* d_in, const int* in_sizes, int n_in,
                              void* d_out, int out_size, void* d_ws, size_t ws_size,
                              hipStream_t stream) {
  (void)in_sizes; (void)n_in; (void)out_size; (void)ws_size;
  const float* h        = (const float*)d_in[0];
  const float* edge_num = (const float*)d_in[1];
  const int*   eidx     = (const int*)d_in[2];
  const float* ew       = (const float*)d_in[3];
  const float* Wsum  = (const float*)d_in[4];  const float* bsum_  = (const float*)d_in[5];
  const float* Wmean = (const float*)d_in[6];  const float* bmean = (const float*)d_in[7];
  const float* Wmax  = (const float*)d_in[8];  const float* bmax  = (const float*)d_in[9];
  const float* Wne   = (const float*)d_in[10]; const float* bne   = (const float*)d_in[11];
  const float* Wnem  = (const float*)d_in[12]; const float* bnem  = (const float*)d_in[13];
  const float* Wl    = (const float*)d_in[14]; const float* Wr    = (const float*)d_in[15];
  const float* We    = (const float*)d_in[16]; const float* att   = (const float*)d_in[17];
  const float* b_att = (const float*)d_in[18];
  const float* Wfc   = (const float*)d_in[19]; const float* bfc   = (const float*)d_in[20];
  const int* src = eidx;
  const int* dst = eidx + N_EDGES;
  float* out = (float*)d_out;

  // workspace layout (~172 MB peak)
  char* p = (char*)d_ws;
  size_t off = 0;
  auto alloc = [&](size_t bytes) { char* r = p + off; off = (off + bytes + 255) & ~(size_t)255; return r; };
  ushort_t* x   = (ushort_t*)alloc((size_t)N_NODES * KP * 2);    // 35.2 MB bf16
  ushort_t* xlr = (ushort_t*)alloc((size_t)N_NODES * HCP * 2);   // 131.2 MB bf16 (padded layout)
  ushort_t* Wt  = (ushort_t*)alloc((size_t)HCP * KP * 2);        // 0.92 MB bf16
  float* yl     = (float*)alloc((size_t)N_NODES * 10 * 4);
  int*   deg    = (int*)alloc((size_t)N_NODES * 4);
  int*   offs   = (int*)alloc((size_t)(N_NODES + 1) * 4);
  int*   cursor = (int*)alloc((size_t)N_NODES * 4);
  int*   csrs   = (int*)alloc((size_t)N_EDGES * 4);
  float* csrw   = (float*)alloc((size_t)N_EDGES * 4);
  int*   bsum   = (int*)alloc((size_t)NBLK * 4);
  int*   bofs   = (int*)alloc((size_t)NBLK * 4);
  float* Wlf    = (float*)alloc((size_t)FDIM * 10 * 4);
  float* red    = (float*)alloc(64);
  float* cvec   = (float*)alloc(64);

  k_init<<<(N_NODES + 255) / 256, 256, 0, stream>>>(deg, cursor, red);
  k_count<<<(N_EDGES + 255) / 256, 256, 0, stream>>>(dst, ew, deg, red);
  k_scan1<<<NBLK, SCAN_B, 0, stream>>>(deg, offs, bsum);
  k_scan2<<<1, 256, 0, stream>>>(bsum, bofs);
  k_scan3<<<NBLK, SCAN_B, 0, stream>>>(bofs, offs);
  k_scatter<<<(N_EDGES + 255) / 256, 256, 0, stream>>>(src, dst, ew, offs, cursor, csrs, csrw);
  k_gcn<<<N_NODES, 64, 0, stream>>>(h, edge_num, offs, csrs, csrw,
                                    Wsum, bsum_, Wmean, bmean, Wmax, bmax,
                                    Wne, bne, Wnem, bnem, x);
  k_wt<<<(HCP * KP + 255) / 256, 256, 0, stream>>>(Wl, Wr, Wt);
  k_gemm_mfma<<<NPAN * NBJ, 256, 0, stream>>>(x, Wt, xlr);   // 4301 blocks, XCD-decoded
  k_wlf<<<(FDIM * 10 + 255) / 256, 256, 0, stream>>>(Wl, Wfc, Wlf);
  k_yl<<<(N_NODES * 64 + 255) / 256, 256, 0, stream>>>(x, Wlf, yl);
  k_cvec<<<1, 64, 0, stream>>>(b_att, Wfc, bfc, red, cvec);
  k_att<<<(N_NODES * 64 + 255) / 256, 256, 0, stream>>>(offs, csrs, csrw, xlr,
                                                        We, att, cvec, yl, out);
}

// Round 14
// 410.433 us; speedup vs baseline: 3.1931x; 1.1308x over previous
//
#include <hip/hip_runtime.h>
#include <hip/hip_bf16.h>
#include <math.h>

#define N_NODES 50000
#define N_EDGES 150000
#define FDIM 325
#define KP 352        // K padded to multiple of 32
#define HCP 1312      // padded xlr row: xl @ [0,650), pad, xr @ [656,1306), pad
#define XROFF 656
#define LDA 40        // LDS A/B tile row stride (ushorts)
#define LDC 136       // LDS C-staging row stride (ushorts)
#define NPAN 391      // M panels (50000/128)
#define NBJ 11        // N blocks (1312/128)
#define SCAN_B 256
#define NBLK ((N_NODES + SCAN_B - 1) / SCAN_B)   // 196

typedef unsigned short ushort_t;
typedef __attribute__((ext_vector_type(8))) short short8v;
typedef __attribute__((ext_vector_type(4))) float f32x4;

__device__ __forceinline__ float bf2f(ushort_t u) {
  return __uint_as_float(((unsigned)u) << 16);
}
__device__ __forceinline__ ushort_t f2bf(float f) {
  __hip_bfloat16 h = __float2bfloat16(f);
  union { __hip_bfloat16 h; ushort_t u; } cv; cv.h = h;
  return cv.u;
}

// ---------------- init ----------------
__global__ void k_init(int* deg, int* cursor, float* red) {
  int i = blockIdx.x * blockDim.x + threadIdx.x;
  if (i < N_NODES) { deg[i] = 0; cursor[i] = 0; }
  if (i == 0) red[0] = 0.f;
}

// ---------------- degree count + edge-weight sum ----------------
__global__ void k_count(const int* __restrict__ dst, const float* __restrict__ ew,
                        int* deg, float* red) {
  int e = blockIdx.x * blockDim.x + threadIdx.x;
  float w = 0.f;
  if (e < N_EDGES) { atomicAdd(&deg[dst[e]], 1); w = ew[e]; }
  #pragma unroll
  for (int m = 32; m; m >>= 1) w += __shfl_xor(w, m);
  if ((threadIdx.x & 63) == 0) atomicAdd(red, w);
}

// ---------------- hierarchical exclusive scan deg -> offs ----------------
__global__ void k_scan1(const int* __restrict__ deg, int* offs, int* bsum) {
  __shared__ int buf[SCAN_B];
  int b = blockIdx.x, tid = threadIdx.x, i = b * SCAN_B + tid;
  int v = (i < N_NODES) ? deg[i] : 0;
  buf[tid] = v;
  __syncthreads();
  for (int o = 1; o < SCAN_B; o <<= 1) {
    int t = (tid >= o) ? buf[tid - o] : 0;
    __syncthreads();
    buf[tid] += t;
    __syncthreads();
  }
  if (i < N_NODES) offs[i + 1] = buf[tid];       // inclusive within block
  if (tid == SCAN_B - 1) bsum[b] = buf[tid];
}
__global__ void k_scan2(const int* __restrict__ bsum, int* bofs) {
  __shared__ int buf[256];
  int tid = threadIdx.x;
  int v = (tid < NBLK) ? bsum[tid] : 0;
  buf[tid] = v;
  __syncthreads();
  for (int o = 1; o < 256; o <<= 1) {
    int t = (tid >= o) ? buf[tid - o] : 0;
    __syncthreads();
    buf[tid] += t;
    __syncthreads();
  }
  if (tid < NBLK) bofs[tid] = buf[tid] - v;      // exclusive block offsets
}
__global__ void k_scan3(const int* __restrict__ bofs, int* offs) {
  int i = blockIdx.x * blockDim.x + threadIdx.x;
  if (i == 0) offs[0] = 0;
  if (i < N_NODES) offs[i + 1] += bofs[i / SCAN_B];
}

// ---------------- scatter edges to CSR (by dst) ----------------
__global__ void k_scatter(const int* __restrict__ src, const int* __restrict__ dst,
                          const float* __restrict__ ew, const int* __restrict__ offs,
                          int* cursor, int* csr_src, float* csr_w) {
  int e = blockIdx.x * blockDim.x + threadIdx.x;
  if (e >= N_EDGES) return;
  int d = dst[e];
  int p = offs[d] + atomicAdd(&cursor[d], 1);
  csr_src[p] = src[e];
  csr_w[p] = ew[e];
}

// ---------------- fused 5x GCNConv aggregation -> x [N,KP] bf16 (K-padded) ----------------
__global__ void __launch_bounds__(64) k_gcn(
    const float* __restrict__ h, const float* __restrict__ edge_num,
    const int* __restrict__ offs, const int* __restrict__ csr_src,
    const float* __restrict__ csr_w,
    const float* __restrict__ Wsum, const float* __restrict__ bsum,
    const float* __restrict__ Wmean, const float* __restrict__ bmean,
    const float* __restrict__ Wmax, const float* __restrict__ bmax,
    const float* __restrict__ Wne, const float* __restrict__ bne,
    const float* __restrict__ Wnem, const float* __restrict__ bnem,
    ushort_t* __restrict__ x) {
  int n = blockIdx.x;
  int t = threadIdx.x;
  float w0[5], w1[5], w2[5], w3[5], w4[5];
  #pragma unroll
  for (int k = 0; k < 5; ++k) {
    w0[k] = Wsum[k * 64 + t];
    w1[k] = Wmean[k * 64 + t];
    w2[k] = Wmax[k * 64 + t];
    w3[k] = Wne[k * 64 + t];
    w4[k] = Wnem[k * 64 + t];
  }
  float s_sum = 0.f, s_wmean = 0.f, s_max = -INFINITY, s_ne = 0.f, s_nem = -INFINITY;
  int beg = offs[n], end = offs[n + 1];
  float wcur = 0.f, hcur[5];
  if (beg < end) {
    int s = csr_src[beg];
    wcur = csr_w[beg];
    #pragma unroll
    for (int k = 0; k < 5; ++k) hcur[k] = h[s * 5 + k];
  }
  for (int i = beg; i < end; ++i) {
    float wnxt = 0.f, hnxt[5];
    if (i + 1 < end) {
      int s = csr_src[i + 1];
      wnxt = csr_w[i + 1];
      #pragma unroll
      for (int k = 0; k < 5; ++k) hnxt[k] = h[s * 5 + k];
    }
    float v0 = 0, v1 = 0, v2 = 0, v3 = 0, v4 = 0;
    #pragma unroll
    for (int k = 0; k < 5; ++k) {
      v0 += hcur[k] * w0[k]; v1 += hcur[k] * w1[k]; v2 += hcur[k] * w2[k];
      v3 += hcur[k] * w3[k]; v4 += hcur[k] * w4[k];
    }
    s_sum += wcur * v0;
    s_wmean += wcur * v1;
    s_max = fmaxf(s_max, wcur * v2);
    s_ne += v3;
    s_nem = fmaxf(s_nem, v4);
    wcur = wnxt;
    #pragma unroll
    for (int k = 0; k < 5; ++k) hcur[k] = hnxt[k];
  }
  int dg = end - beg;
  float inv = 1.f / (float)(dg > 0 ? dg : 1);
  ushort_t* xr = x + (size_t)n * KP;
  xr[t]       = f2bf(s_sum + bsum[t]);
  xr[64 + t]  = f2bf(s_wmean * inv + bmean[t]);
  xr[128 + t] = f2bf((dg ? s_max : 0.f) + bmax[t]);
  xr[192 + t] = f2bf(s_ne + bne[t]);
  xr[256 + t] = f2bf((dg ? s_nem : 0.f) + bnem[t]);
  if (t < 5) xr[320 + t] = f2bf(edge_num[n * 5 + t]);
  if (t < KP - FDIM) xr[FDIM + t] = 0;   // zero-pad K 325..351
}

// ---------------- Wt[HCP][KP] bf16: [Wl | pad | Wr | pad]^T, k-contiguous ----------------
__global__ void k_wt(const float* __restrict__ Wl, const float* __restrict__ Wr,
                     ushort_t* __restrict__ Wt) {
  int t = blockIdx.x * blockDim.x + threadIdx.x;
  if (t >= HCP * KP) return;
  int n = t / KP, k = t % KP;
  float v = 0.f;
  if (k < FDIM) {
    if (n < 650) v = Wl[(size_t)k * 650 + n];
    else if (n >= XROFF && n < XROFF + 650) v = Wr[(size_t)k * 650 + (n - XROFF)];
  }
  Wt[t] = f2bf(v);
}

// ---------------- MFMA GEMM: xlr[N,HCP] (bf16) = x[N,325] @ Wt^T ----------------
// Register-prefetch staging: step k+1's global loads issue right after the
// first barrier of step k, flying during ds_read+MFMA; vmcnt drains at the
// next ds_write, by which time MFMA has covered the HBM latency.
__global__ void __launch_bounds__(256) k_gemm_mfma(
    const ushort_t* __restrict__ x, const ushort_t* __restrict__ Wt,
    ushort_t* __restrict__ xlr) {
  __shared__ ushort_t smem[128 * LDA * 2];   // As | Bs ; reused as Cs in epilogue
  ushort_t* As = smem;
  ushort_t* Bs = smem + 128 * LDA;
  ushort_t* Cs = smem;                       // 64 x LDC <= 2*128*LDA

  // ---- XCD-aware block decode ----
  int L = blockIdx.x;
  int panel, jb;
  if (L < 4224) {            // 48 chunks x (8 panels x 11 jb)
    int chunk = L / 88, g = L % 88;
    panel = chunk * 8 + (g & 7);
    jb = g >> 3;
  } else {                   // remainder: 7 panels x 11 jb
    int g = L - 4224;
    panel = 384 + g % 7;
    jb = g / 7;
  }
  int bm = panel * 128, bn = jb * 128;

  int tid = threadIdx.x;
  int lane = tid & 63, wave = tid >> 6;
  int wr = wave >> 1, wc = wave & 1;         // 2x2 waves, each owns 64x64 of C
  int srow = tid >> 2, skc = (tid & 3) << 3; // staging: rows srow, srow+64
  const float4 fz = make_float4(0.f, 0.f, 0.f, 0.f);

  float4 pa0, pa1, pb0, pb1;
  {   // prologue: load K-step 0
    int gm0 = bm + srow, gm1 = gm0 + 64;
    int gn0 = bn + srow, gn1 = gn0 + 64;
    pa0 = (gm0 < N_NODES) ? *(const float4*)&x[(size_t)gm0 * KP + skc] : fz;
    pa1 = (gm1 < N_NODES) ? *(const float4*)&x[(size_t)gm1 * KP + skc] : fz;
    pb0 = (gn0 < HCP)     ? *(const float4*)&Wt[(size_t)gn0 * KP + skc] : fz;
    pb1 = (gn1 < HCP)     ? *(const float4*)&Wt[(size_t)gn1 * KP + skc] : fz;
  }
  f32x4 acc[4][4] = {};
  for (int k0 = 0; k0 < KP; k0 += 32) {
    // write prefetched step to LDS (vmcnt waits here)
    *(float4*)&As[srow * LDA + skc]        = pa0;
    *(float4*)&As[(srow + 64) * LDA + skc] = pa1;
    *(float4*)&Bs[srow * LDA + skc]        = pb0;
    *(float4*)&Bs[(srow + 64) * LDA + skc] = pb1;
    __syncthreads();
    // issue next step's loads now — they fly during ds_read + MFMA
    int kn = k0 + 32;
    if (kn < KP) {
      int gm0 = bm + srow, gm1 = gm0 + 64;
      int gn0 = bn + srow, gn1 = gn0 + 64;
      pa0 = (gm0 < N_NODES) ? *(const float4*)&x[(size_t)gm0 * KP + kn + skc] : fz;
      pa1 = (gm1 < N_NODES) ? *(const float4*)&x[(size_t)gm1 * KP + kn + skc] : fz;
      pb0 = (gn0 < HCP)     ? *(const float4*)&Wt[(size_t)gn0 * KP + kn + skc] : fz;
      pb1 = (gn1 < HCP)     ? *(const float4*)&Wt[(size_t)gn1 * KP + kn + skc] : fz;
    }
    int koff = (lane >> 4) << 3;             // 0,8,16,24
    int ar = (wr << 6) + (lane & 15);
    int br = (wc << 6) + (lane & 15);
    short8v a[4], b[4];
    #pragma unroll
    for (int i = 0; i < 4; ++i) a[i] = *(const short8v*)&As[(ar + i * 16) * LDA + koff];
    #pragma unroll
    for (int j = 0; j < 4; ++j) b[j] = *(const short8v*)&Bs[(br + j * 16) * LDA + koff];
    #pragma unroll
    for (int i = 0; i < 4; ++i)
      #pragma unroll
      for (int j = 0; j < 4; ++j)
        acc[i][j] = __builtin_amdgcn_mfma_f32_16x16x32_bf16(a[i], b[j], acc[i][j], 0, 0, 0);
    __syncthreads();
  }
  // ---- epilogue: stage 64-row halves in LDS, write out coalesced 16B chunks ----
  #pragma unroll
  for (int half = 0; half < 2; ++half) {
    if (wr == half) {
      int lr0 = ((lane >> 4) << 2);
      int c0 = (wc << 6) + (lane & 15);
      #pragma unroll
      for (int i = 0; i < 4; ++i)
        #pragma unroll
        for (int j = 0; j < 4; ++j)
          #pragma unroll
          for (int r = 0; r < 4; ++r)
            Cs[(lr0 + i * 16 + r) * LDC + c0 + j * 16] = f2bf(acc[i][j][r]);
    }
    __syncthreads();
    #pragma unroll
    for (int it = 0; it < 4; ++it) {
      int idx = tid + it * 256;              // 0..1023 = 64 rows x 16 chunks
      int lr = idx >> 4, cc = idx & 15;
      int row = bm + half * 64 + lr;
      int col = bn + cc * 8;
      if (row < N_NODES && col < HCP) {
        short8v v = *(const short8v*)&Cs[lr * LDC + cc * 8];
        *(short8v*)&xlr[(size_t)row * HCP + col] = v;
      }
    }
    __syncthreads();
  }
}

// ---------------- Wlf[325,10] = per-head Wl @ Wfc fusion ----------------
__global__ void k_wlf(const float* __restrict__ Wl, const float* __restrict__ Wfc,
                      float* __restrict__ Wlf) {
  int t = blockIdx.x * blockDim.x + threadIdx.x;
  if (t >= FDIM * 10) return;
  int cp = t / 10, o = t % 10;
  int hh = o / 5, j = o % 5;
  float s = 0.f;
  for (int c = 0; c < 325; ++c) s += Wl[(size_t)cp * 650 + hh * 325 + c] * Wfc[c * 5 + j];
  Wlf[cp * 10 + o] = s;
}

// ---------------- yl[N,2,5] = x @ Wlf (f32 accumulate) ----------------
__global__ void k_yl(const ushort_t* __restrict__ x, const float* __restrict__ Wlf,
                     float* __restrict__ yl) {
  int wid = (blockIdx.x * blockDim.x + threadIdx.x) >> 6;
  int lane = threadIdx.x & 63;
  if (wid >= N_NODES) return;
  const ushort_t* row = x + (size_t)wid * KP;
  float p[10] = {};
  for (int c = lane; c < FDIM; c += 64) {
    float v = bf2f(row[c]);
    const float* wr = Wlf + c * 10;
    #pragma unroll
    for (int j = 0; j < 10; ++j) p[j] += v * wr[j];
  }
  #pragma unroll
  for (int j = 0; j < 10; ++j)
    #pragma unroll
    for (int m = 32; m; m >>= 1) p[j] += __shfl_xor(p[j], m);
  if (lane == 0) {
    #pragma unroll
    for (int j = 0; j < 10; ++j) yl[(size_t)wid * 10 + j] = p[j];
  }
}

// ---------------- cvec[j] = b_att @ W_fc1 + b_fc1 ; cvec[5] = mean(ew) ----------------
__global__ void k_cvec(const float* __restrict__ b_att, const float* __restrict__ Wfc,
                       const float* __restrict__ b_fc1, const float* __restrict__ red,
                       float* __restrict__ cvec) {
  int j = threadIdx.x;
  if (j == 5) cvec[5] = red[0] / (float)N_EDGES;
  if (j < 5) {
    float s = b_fc1[j];
    for (int c = 0; c < 325; ++c) s += b_att[c] * Wfc[c * 5 + j];
    cvec[j] = s;
  }
}

// ---------------- fused GATv2 attention: 1 wave = 1 dst node ----------------
// block=64 removes the 4-wave-per-block straggler waste (Poisson degrees:
// E[max of 4] ~ 5.5 vs 4); software-pipelined loads retained.
__global__ void __launch_bounds__(64) k_att(
    const int* __restrict__ offs, const int* __restrict__ csrs,
    const float* __restrict__ csrw, const ushort_t* __restrict__ xlr,
    const float* __restrict__ We, const float* __restrict__ att,
    const float* __restrict__ cvec, const float* __restrict__ yl,
    float* __restrict__ out) {
  int d = blockIdx.x;
  int lane = threadIdx.x;
  float xd0[8], xd1[8], We0[8], We1[8], at0[8], at1[8];
  const ushort_t* xd = xlr + (size_t)d * HCP + XROFF;
  {
    short8v v = *(const short8v*)&xd[lane * 8];
    int c0 = lane * 8;
    #pragma unroll
    for (int e = 0; e < 8; ++e) {
      xd0[e] = bf2f((ushort_t)v[e]);
      We0[e] = We[c0 + e];
      at0[e] = att[c0 + e];
    }
  }
  if (lane < 18) {
    short8v v = *(const short8v*)&xd[512 + lane * 8];
    int c0 = 512 + lane * 8;
    #pragma unroll
    for (int e = 0; e < 8; ++e) {
      bool ok = (c0 + e) < 650;
      xd1[e] = bf2f((ushort_t)v[e]);
      We1[e] = ok ? We[c0 + e] : 0.f;
      at1[e] = ok ? att[c0 + e] : 0.f;
    }
  }
  float meanw = cvec[5];
  int beg = offs[d], end = offs[d + 1];
  float m0 = -INFINITY, m1 = -INFINITY, s0 = 0.f, s1 = 0.f;
  float oj = 0.f;   // lanes 0..9: o_j (j<5 head0 dims, j>=5 head1 dims)

  // prologue: load edge `beg` (or the self-loop if degree==0)
  float ea_c, yv_c = 0.f;
  short8v v0_c, v1_c;
  {
    int s;
    if (beg < end) { s = csrs[beg]; ea_c = csrw[beg]; }
    else { s = d; ea_c = meanw; }
    const ushort_t* xs = xlr + (size_t)s * HCP;
    v0_c = *(const short8v*)&xs[lane * 8];
    if (lane < 18) v1_c = *(const short8v*)&xs[512 + lane * 8];
    if (lane < 10) yv_c = yl[(size_t)s * 10 + lane];
  }
  for (int i = beg; i <= end; ++i) {
    // ---- prefetch edge i+1 ----
    float ea_n = 0.f, yv_n = 0.f;
    short8v v0_n, v1_n;
    bool have_next = (i < end);
    if (have_next) {
      int s;
      if (i + 1 < end) { s = csrs[i + 1]; ea_n = csrw[i + 1]; }
      else { s = d; ea_n = meanw; }
      const ushort_t* xs = xlr + (size_t)s * HCP;
      v0_n = *(const short8v*)&xs[lane * 8];
      if (lane < 18) v1_n = *(const short8v*)&xs[512 + lane * 8];
      if (lane < 10) yv_n = yl[(size_t)s * 10 + lane];
    }
    // ---- compute with current edge ----
    float p0 = 0.f, p1 = 0.f;
    {
      int c0 = lane * 8;
      #pragma unroll
      for (int e = 0; e < 8; ++e) {
        float vv = bf2f((ushort_t)v0_c[e]) + xd0[e] + ea_c * We0[e];
        vv = (vv > 0.f) ? vv : 0.2f * vv;
        float t = vv * at0[e];
        if (c0 + e < 325) p0 += t; else p1 += t;
      }
    }
    if (lane < 18) {
      #pragma unroll
      for (int e = 0; e < 8; ++e) {
        float vv = bf2f((ushort_t)v1_c[e]) + xd1[e] + ea_c * We1[e];
        vv = (vv > 0.f) ? vv : 0.2f * vv;
        p1 += vv * at1[e];   // pads masked by at1=0
      }
    }
    #pragma unroll
    for (int m = 32; m; m >>= 1) { p0 += __shfl_xor(p0, m); p1 += __shfl_xor(p1, m); }
    float nm0 = fmaxf(m0, p0), nm1 = fmaxf(m1, p1);
    float r0 = __expf(m0 - nm0), r1 = __expf(m1 - nm1);  // first iter: exp(-inf)=0
    float e0 = __expf(p0 - nm0), e1 = __expf(p1 - nm1);
    s0 = s0 * r0 + e0; s1 = s1 * r1 + e1;
    m0 = nm0; m1 = nm1;
    if (lane < 10) {
      float r = (lane < 5) ? r0 : r1;
      float e = (lane < 5) ? e0 : e1;
      oj = oj * r + e * yv_c;
    }
    // ---- rotate pipeline ----
    if (have_next) { ea_c = ea_n; yv_c = yv_n; v0_c = v0_n; v1_c = v1_n; }
  }
  float on = oj / ((lane < 5) ? s0 : s1);
  float other = __shfl(on, lane + 5);
  if (lane < 5) {
    int dg = end - beg;
    out[(size_t)d * 5 + lane] = (on + other) / (2.f * (float)(dg + 1)) + cvec[lane];
  }
}

extern "C" void kernel_launch(void* const* d_in, const int* in_sizes, int n_in,
                              void* d_out, int out_size, void* d_ws, size_t ws_size,
                              hipStream_t stream) {
  (void)in_sizes; (void)n_in; (void)out_size; (void)ws_size;
  const float* h        = (const float*)d_in[0];
  const float* edge_num = (const float*)d_in[1];
  const int*   eidx     = (const int*)d_in[2];
  const float* ew       = (const float*)d_in[3];
  const float* Wsum  = (const float*)d_in[4];  const float* bsum_  = (const float*)d_in[5];
  const float* Wmean = (const float*)d_in[6];  const float* bmean = (const float*)d_in[7];
  const float* Wmax  = (const float*)d_in[8];  const float* bmax  = (const float*)d_in[9];
  const float* Wne   = (const float*)d_in[10]; const float* bne   = (const float*)d_in[11];
  const float* Wnem  = (const float*)d_in[12]; const float* bnem  = (const float*)d_in[13];
  const float* Wl    = (const float*)d_in[14]; const float* Wr    = (const float*)d_in[15];
  const float* We    = (const float*)d_in[16]; const float* att   = (const float*)d_in[17];
  const float* b_att = (const float*)d_in[18];
  const float* Wfc   = (const float*)d_in[19]; const float* bfc   = (const float*)d_in[20];
  const int* src = eidx;
  const int* dst = eidx + N_EDGES;
  float* out = (float*)d_out;

  // workspace layout (~172 MB peak)
  char* p = (char*)d_ws;
  size_t off = 0;
  auto alloc = [&](size_t bytes) { char* r = p + off; off = (off + bytes + 255) & ~(size_t)255; return r; };
  ushort_t* x   = (ushort_t*)alloc((size_t)N_NODES * KP * 2);    // 35.2 MB bf16
  ushort_t* xlr = (ushort_t*)alloc((size_t)N_NODES * HCP * 2);   // 131.2 MB bf16 (padded layout)
  ushort_t* Wt  = (ushort_t*)alloc((size_t)HCP * KP * 2);        // 0.92 MB bf16
  float* yl     = (float*)alloc((size_t)N_NODES * 10 * 4);
  int*   deg    = (int*)alloc((size_t)N_NODES * 4);
  int*   offs   = (int*)alloc((size_t)(N_NODES + 1) * 4);
  int*   cursor = (int*)alloc((size_t)N_NODES * 4);
  int*   csrs   = (int*)alloc((size_t)N_EDGES * 4);
  float* csrw   = (float*)alloc((size_t)N_EDGES * 4);
  int*   bsum   = (int*)alloc((size_t)NBLK * 4);
  int*   bofs   = (int*)alloc((size_t)NBLK * 4);
  float* Wlf    = (float*)alloc((size_t)FDIM * 10 * 4);
  float* red    = (float*)alloc(64);
  float* cvec   = (float*)alloc(64);

  k_init<<<(N_NODES + 255) / 256, 256, 0, stream>>>(deg, cursor, red);
  k_count<<<(N_EDGES + 255) / 256, 256, 0, stream>>>(dst, ew, deg, red);
  k_scan1<<<NBLK, SCAN_B, 0, stream>>>(deg, offs, bsum);
  k_scan2<<<1, 256, 0, stream>>>(bsum, bofs);
  k_scan3<<<NBLK, SCAN_B, 0, stream>>>(bofs, offs);
  k_scatter<<<(N_EDGES + 255) / 256, 256, 0, stream>>>(src, dst, ew, offs, cursor, csrs, csrw);
  k_gcn<<<N_NODES, 64, 0, stream>>>(h, edge_num, offs, csrs, csrw,
                                    Wsum, bsum_, Wmean, bmean, Wmax, bmax,
                                    Wne, bne, Wnem, bnem, x);
  k_wt<<<(HCP * KP + 255) / 256, 256, 0, stream>>>(Wl, Wr, Wt);
  k_gemm_mfma<<<NPAN * NBJ, 256, 0, stream>>>(x, Wt, xlr);   // 4301 blocks, XCD-decoded
  k_wlf<<<(FDIM * 10 + 255) / 256, 256, 0, stream>>>(Wl, Wfc, Wlf);
  k_yl<<<(N_NODES * 64 + 255) / 256, 256, 0, stream>>>(x, Wlf, yl);
  k_cvec<<<1, 64, 0, stream>>>(b_att, Wfc, bfc, red, cvec);
  k_att<<<N_NODES, 64, 0, stream>>>(offs, csrs, csrw, xlr, We, att, cvec, yl, out);
}